// Round 3
// baseline (737.507 us; speedup 1.0000x reference)
//
#include <hip/hip_runtime.h>

#define F 64
#define TPB 256
#define SCAN_B 64
#define BN_EPS 1e-5f
#define NPW 4

typedef unsigned short u16;
typedef __attribute__((ext_vector_type(8))) short v8s;
typedef __attribute__((ext_vector_type(4))) float v4f;

__device__ __forceinline__ float lane_bcast(float v, int l) {
    return __int_as_float(__builtin_amdgcn_readlane(__float_as_int(v), l));
}
__device__ __forceinline__ int lane_bcast_i(int v, int l) {
    return __builtin_amdgcn_readlane(v, l);
}
__device__ __forceinline__ float bf2f(u16 u) {
    return __uint_as_float(((unsigned int)u) << 16);
}
__device__ __forceinline__ u16 f2bf(float f) {
    unsigned int u = __float_as_uint(f);
    unsigned int r = (u + 0x7fffu + ((u >> 16) & 1u)) >> 16;   // RNE
    return (u16)r;
}

// ---- CSR build ----------------------------------------------------------

__global__ __launch_bounds__(TPB) void k_hist(const int* __restrict__ dst,
                                              int* __restrict__ deg, int E) {
    int e = blockIdx.x * blockDim.x + threadIdx.x;
    if (e < E) atomicAdd(&deg[dst[e]], 1);
}

__global__ __launch_bounds__(TPB) void k_scan_part(const int* __restrict__ deg,
                                                   int* __restrict__ part, int N) {
    __shared__ int red[TPB];
    int chunk = (N + SCAN_B - 1) / SCAN_B;
    int lo = blockIdx.x * chunk, hi = min(lo + chunk, N);
    int t = threadIdx.x;
    int s = 0;
    for (int i = lo + t; i < hi; i += TPB) s += deg[i];
    red[t] = s; __syncthreads();
    for (int d = TPB / 2; d > 0; d >>= 1) {
        if (t < d) red[t] += red[t + d];
        __syncthreads();
    }
    if (t == 0) part[blockIdx.x] = red[0];
}

__global__ __launch_bounds__(TPB) void k_scan_apply(const int* __restrict__ deg,
                                                    const int* __restrict__ part,
                                                    int* __restrict__ offs,
                                                    int* __restrict__ cursor, int N) {
    __shared__ int ts[TPB];
    __shared__ int pb_s;
    int t = threadIdx.x;
    ts[t] = (t < blockIdx.x) ? part[t] : 0;
    __syncthreads();
    for (int d = TPB / 2; d > 0; d >>= 1) {
        if (t < d) ts[t] += ts[t + d];
        __syncthreads();
    }
    if (t == 0) pb_s = ts[0];
    __syncthreads();
    int pbase = pb_s;
    __syncthreads();
    int chunk = (N + SCAN_B - 1) / SCAN_B;
    int sub = (chunk + TPB - 1) / TPB;
    int lo = blockIdx.x * chunk;
    int blockhi = min(lo + chunk, N);
    int mylo = min(lo + t * sub, blockhi);
    int myhi = min(mylo + sub, blockhi);
    int s = 0;
    for (int i = mylo; i < myhi; ++i) s += deg[i];
    ts[t] = s; __syncthreads();
    for (int d = 1; d < TPB; d <<= 1) {
        int a = (t >= d) ? ts[t - d] : 0;
        __syncthreads();
        ts[t] += a;
        __syncthreads();
    }
    int run = pbase + ts[t] - s;
    for (int i = mylo; i < myhi; ++i) {
        offs[i] = run; cursor[i] = run; run += deg[i];
    }
    if (blockIdx.x == SCAN_B - 1 && t == TPB - 1) offs[N] = pbase + ts[TPB - 1];
}

__global__ __launch_bounds__(TPB) void k_fill(const int* __restrict__ src,
                                              const int* __restrict__ dst,
                                              int* __restrict__ cursor,
                                              int* __restrict__ csr_src, int E) {
    int e = blockIdx.x * blockDim.x + threadIdx.x;
    if (e >= E) return;
    int pos = atomicAdd(&cursor[dst[e]], 1);
    csr_src[pos] = src[e];
}

// ---- MFMA prep: x16 = bf16(x); Yf = x @ Wj + bias -----------------------
__global__ __launch_bounds__(TPB, 4)
void k_prep(const float* __restrict__ x, u16* __restrict__ x16,
            const float* __restrict__ Wj, const float* __restrict__ bias,
            float* __restrict__ Yf, int N) {
    __shared__ u16 Wjl[F * F];
    int t = threadIdx.x;
    int lane = t & 63, w = t >> 6;
    int m16 = lane & 15, quad = lane >> 4;
    for (int i = t; i < F * F; i += TPB) Wjl[i] = f2bf(Wj[i]);
    __syncthreads();
    int row0 = (blockIdx.x * 4 + w) * 16;
    if (row0 >= N) return;
    v8s bfj[4][2];
#pragma unroll
    for (int nt = 0; nt < 4; ++nt)
#pragma unroll
        for (int kc = 0; kc < 2; ++kc)
#pragma unroll
            for (int j = 0; j < 8; ++j)
                bfj[nt][kc][j] = (short)Wjl[(kc * 32 + quad * 8 + j) * F + nt * 16 + m16];
    v8s a[2];
#pragma unroll
    for (int kc = 0; kc < 2; ++kc) {
        const float* xp = x + (size_t)(row0 + m16) * F + kc * 32 + quad * 8;
        float4 r0 = *(const float4*)xp;
        float4 r1 = *(const float4*)(xp + 4);
        u16 b[8] = {f2bf(r0.x), f2bf(r0.y), f2bf(r0.z), f2bf(r0.w),
                    f2bf(r1.x), f2bf(r1.y), f2bf(r1.z), f2bf(r1.w)};
#pragma unroll
        for (int j = 0; j < 8; ++j) a[kc][j] = (short)b[j];
        *(uint4*)(x16 + (size_t)(row0 + m16) * F + kc * 32 + quad * 8) = *(const uint4*)b;
    }
#pragma unroll
    for (int nt = 0; nt < 4; ++nt) {
        float bb = bias[nt * 16 + m16];
        v4f acc = {bb, bb, bb, bb};
        acc = __builtin_amdgcn_mfma_f32_16x16x32_bf16(a[0], bfj[nt][0], acc, 0, 0, 0);
        acc = __builtin_amdgcn_mfma_f32_16x16x32_bf16(a[1], bfj[nt][1], acc, 0, 0, 0);
#pragma unroll
        for (int reg = 0; reg < 4; ++reg)
            Yf[(size_t)(row0 + quad * 4 + reg) * F + nt * 16 + m16] = acc[reg];
    }
}

// ---- fused gather + MFMA GEMM1 + BN stats -------------------------------
// R0-verified gather inner loop (16-deep dense batches, branch-free sums,
// per-node idx prefetch) with NPW=4: each wave owns 4 nodes, block owns 16,
// grid = 3125 blocks (12.2/CU) so ~8 blocks stay resident and the queue
// smooths the degree-imbalance tail that capped R0 occupancy at 37%.
#define HPAD 72   // row stride in u16 (16B-aligned)

__global__ __launch_bounds__(TPB, 8)
void k_gather_gemm(const u16* __restrict__ h, const int* __restrict__ offs,
                   const int* __restrict__ csr,
                   const float* __restrict__ W, const float* __restrict__ bias,
                   u16* __restrict__ Y16, float* __restrict__ stats, int N) {
    __shared__ u16 Wlt[F * HPAD];     // W transposed, bf16: Wlt[n*HPAD + k]
    __shared__ u16 hb[16 * HPAD];     // gathered agg rows, bf16
    __shared__ float cred[2 * F];
    int t = threadIdx.x;
    int lane = t & 63, w = t >> 6;
    int m16 = lane & 15, quad = lane >> 4;
    for (int i = t; i < F * F; i += TPB)
        Wlt[(i & (F - 1)) * HPAD + (i >> 6)] = f2bf(W[i]);   // i = k*F + n
    if (t < 2 * F) cred[t] = 0.f;

    int node0 = blockIdx.x * 16 + w * NPW;
    int off_l = 0;
    if (lane <= NPW) off_l = offs[min(node0 + lane, N)];
    int start_n = lane_bcast_i(off_l, 0);
    int end_n   = lane_bcast_i(off_l, 1);
    int cnt_n   = min(end_n - start_n, 64);
    int idx_n   = (lane < cnt_n) ? csr[start_n + lane] : 0;
    for (int r = 0; r < NPW; ++r) {
        int node = node0 + r;
        int start = start_n, end = end_n, cnt = cnt_n, idx = idx_n;
        if (r + 1 < NPW) {
            start_n = lane_bcast_i(off_l, r + 1);
            end_n   = lane_bcast_i(off_l, r + 2);
            cnt_n   = min(end_n - start_n, 64);
            idx_n   = (lane < cnt_n) ? csr[start_n + lane] : 0;
        }
        if (node >= N) { hb[(w * NPW + r) * HPAD + lane] = 0; continue; }
        float agg = bf2f(h[(size_t)node * F + lane]);    // GIN self term (eps=0)
        {
            int k = 0;
            for (; k + 16 <= cnt; k += 16) {
                float vv[16];
#pragma unroll
                for (int u = 0; u < 16; ++u)
                    vv[u] = bf2f(h[(size_t)lane_bcast_i(idx, k + u) * F + lane]);
                float sA = 0.f, sB = 0.f, sC = 0.f, sD = 0.f;
#pragma unroll
                for (int u = 0; u < 4; ++u) {
                    sA += vv[u]; sB += vv[4 + u]; sC += vv[8 + u]; sD += vv[12 + u];
                }
                agg += (sA + sB) + (sC + sD);
            }
            for (; k + 4 <= cnt; k += 4) {
                float v0 = bf2f(h[(size_t)lane_bcast_i(idx, k)     * F + lane]);
                float v1 = bf2f(h[(size_t)lane_bcast_i(idx, k + 1) * F + lane]);
                float v2 = bf2f(h[(size_t)lane_bcast_i(idx, k + 2) * F + lane]);
                float v3 = bf2f(h[(size_t)lane_bcast_i(idx, k + 3) * F + lane]);
                agg += (v0 + v1) + (v2 + v3);
            }
            for (; k < cnt; ++k)
                agg += bf2f(h[(size_t)lane_bcast_i(idx, k) * F + lane]);
        }
        for (int base = start + 64; base < end; base += 64) {
            int c2 = end - base; if (c2 > 64) c2 = 64;
            int idx2 = (lane < c2) ? csr[base + lane] : 0;
            int k = 0;
            for (; k + 4 <= c2; k += 4) {
                float v0 = bf2f(h[(size_t)lane_bcast_i(idx2, k)     * F + lane]);
                float v1 = bf2f(h[(size_t)lane_bcast_i(idx2, k + 1) * F + lane]);
                float v2 = bf2f(h[(size_t)lane_bcast_i(idx2, k + 2) * F + lane]);
                float v3 = bf2f(h[(size_t)lane_bcast_i(idx2, k + 3) * F + lane]);
                agg += (v0 + v1) + (v2 + v3);
            }
            for (; k < c2; ++k)
                agg += bf2f(h[(size_t)lane_bcast_i(idx2, k) * F + lane]);
        }
        hb[(w * NPW + r) * HPAD + lane] = f2bf(agg);
    }
    __syncthreads();

    // MFMA phase: wave w computes column tile w (cols w*16 .. w*16+15)
    int col = w * 16 + m16;
    v8s a0  = *(const v8s*)(hb + m16 * HPAD + quad * 8);
    v8s a1  = *(const v8s*)(hb + m16 * HPAD + 32 + quad * 8);
    v8s bv0 = *(const v8s*)(Wlt + col * HPAD + quad * 8);
    v8s bv1 = *(const v8s*)(Wlt + col * HPAD + 32 + quad * 8);
    float bb = bias[col];
    v4f acc = {bb, bb, bb, bb};
    acc = __builtin_amdgcn_mfma_f32_16x16x32_bf16(a0, bv0, acc, 0, 0, 0);
    acc = __builtin_amdgcn_mfma_f32_16x16x32_bf16(a1, bv1, acc, 0, 0, 0);
    int rowbase = blockIdx.x * 16;
    float ss1 = 0.f, ss2 = 0.f;
#pragma unroll
    for (int reg = 0; reg < 4; ++reg) {
        int row = rowbase + quad * 4 + reg;
        if (row < N) {
            float yv = acc[reg];
            Y16[(size_t)row * F + col] = f2bf(yv);
            ss1 += yv; ss2 += yv * yv;
        }
    }
    atomicAdd(&cred[col], ss1);
    atomicAdd(&cred[F + col], ss2);
    __syncthreads();
    if (t < 2 * F) atomicAdd(&stats[t], cred[t]);
}

// ---- MFMA layerB (R19-verified) -----------------------------------------
__global__ __launch_bounds__(TPB, 3)
void k_layerB(const u16* __restrict__ Y16, const float* __restrict__ stats,
              const float* __restrict__ g, const float* __restrict__ bt,
              const float* __restrict__ W2, const float* __restrict__ b2,
              const float* __restrict__ Wj,
              u16* __restrict__ Hout, float* __restrict__ Yf,
              float* __restrict__ stats5, int N, int doHead) {
    __shared__ u16 W2l[F * F];
    __shared__ u16 Wjl[F * F];
    __shared__ float scs[F], shs[F];
    __shared__ u16 hbuf[4][16 * F];
    __shared__ float cred1[F], cred2[F];
    int t = threadIdx.x;
    int lane = t & 63, w = t >> 6;
    int m16 = lane & 15, quad = lane >> 4;
    for (int i = t; i < F * F; i += TPB) {
        W2l[i] = f2bf(W2[i]);
        Wjl[i] = f2bf(Wj[i]);
    }
    if (t < F) {
        float mu = stats[t] / (float)N;
        float var = stats[F + t] / (float)N - mu * mu;
        float rs = rsqrtf(var + BN_EPS);
        float sc = rs * g[t];
        scs[t] = sc;
        shs[t] = bt[t] - mu * sc;
    }
    __syncthreads();

    int row0 = (blockIdx.x * 4 + w) * 16;
    float s1v[4] = {0.f, 0.f, 0.f, 0.f}, s2v[4] = {0.f, 0.f, 0.f, 0.f};
    if (row0 < N) {
        v8s bf2_[4][2], bfj_[4][2];
#pragma unroll
        for (int nt = 0; nt < 4; ++nt)
#pragma unroll
            for (int kc = 0; kc < 2; ++kc)
#pragma unroll
                for (int j = 0; j < 8; ++j) {
                    int k = kc * 32 + quad * 8 + j;
                    bf2_[nt][kc][j] = (short)W2l[k * F + nt * 16 + m16];
                    bfj_[nt][kc][j] = (short)Wjl[k * F + nt * 16 + m16];
                }
        v8s a1[2];
#pragma unroll
        for (int kc = 0; kc < 2; ++kc) {
            uint4 raw = *(const uint4*)(Y16 + (size_t)(row0 + m16) * F + kc * 32 + quad * 8);
            unsigned uu[4] = {raw.x, raw.y, raw.z, raw.w};
#pragma unroll
            for (int p = 0; p < 4; ++p) {
                int k0 = kc * 32 + quad * 8 + 2 * p;
                float lo = __uint_as_float(uu[p] << 16);
                float hi = __uint_as_float(uu[p] & 0xffff0000u);
                float v0 = fmaxf(lo * scs[k0] + shs[k0], 0.f);
                float v1 = fmaxf(hi * scs[k0 + 1] + shs[k0 + 1], 0.f);
                a1[kc][2 * p]     = (short)f2bf(v0);
                a1[kc][2 * p + 1] = (short)f2bf(v1);
            }
        }
        u16* hb = hbuf[w];
#pragma unroll
        for (int nt = 0; nt < 4; ++nt) {
            float bb = b2[nt * 16 + m16];
            v4f acc = {bb, bb, bb, bb};
            acc = __builtin_amdgcn_mfma_f32_16x16x32_bf16(a1[0], bf2_[nt][0], acc, 0, 0, 0);
            acc = __builtin_amdgcn_mfma_f32_16x16x32_bf16(a1[1], bf2_[nt][1], acc, 0, 0, 0);
#pragma unroll
            for (int reg = 0; reg < 4; ++reg)
                hb[(quad * 4 + reg) * F + nt * 16 + m16] = f2bf(fmaxf(acc[reg], 0.f));
        }
#pragma unroll
        for (int rr = 0; rr < 4; ++rr) {
            int row = rr * 4 + quad;
            uint2 d = *(const uint2*)(hb + row * F + m16 * 4);
            *(uint2*)(Hout + (size_t)(row0 + row) * F + m16 * 4) = d;
        }
        v8s a2[2];
#pragma unroll
        for (int kc = 0; kc < 2; ++kc)
            a2[kc] = *(const v8s*)(hb + m16 * F + kc * 32 + quad * 8);
#pragma unroll
        for (int nt = 0; nt < 4; ++nt) {
            v4f acc;
#pragma unroll
            for (int reg = 0; reg < 4; ++reg)
                acc[reg] = Yf[(size_t)(row0 + quad * 4 + reg) * F + nt * 16 + m16];
            acc = __builtin_amdgcn_mfma_f32_16x16x32_bf16(a2[0], bfj_[nt][0], acc, 0, 0, 0);
            acc = __builtin_amdgcn_mfma_f32_16x16x32_bf16(a2[1], bfj_[nt][1], acc, 0, 0, 0);
            float ss1 = 0.f, ss2 = 0.f;
#pragma unroll
            for (int reg = 0; reg < 4; ++reg) {
                float yv = acc[reg];
                Yf[(size_t)(row0 + quad * 4 + reg) * F + nt * 16 + m16] = yv;
                ss1 += yv;
                ss2 += yv * yv;
            }
            s1v[nt] = ss1;
            s2v[nt] = ss2;
        }
    }
    if (doHead) {
        if (t < F) { cred1[t] = 0.f; cred2[t] = 0.f; }
        __syncthreads();
        if (row0 < N) {
#pragma unroll
            for (int nt = 0; nt < 4; ++nt) {
                atomicAdd(&cred1[nt * 16 + m16], s1v[nt]);
                atomicAdd(&cred2[nt * 16 + m16], s2v[nt]);
            }
        }
        __syncthreads();
        if (t < F) {
            atomicAdd(&stats5[t], cred1[t]);
            atomicAdd(&stats5[F + t], cred2[t]);
        }
    }
}

// ---- MFMA head: BN(Yf)+ReLU -> @mlpW2+b2 -> pooled add into out[graph] --
__global__ __launch_bounds__(TPB, 4)
void k_final(const float* __restrict__ Yf, const float* __restrict__ stats,
             const float* __restrict__ g, const float* __restrict__ bt,
             const float* __restrict__ W2, const float* __restrict__ b2,
             const int* __restrict__ batch, float* __restrict__ out, int N) {
    __shared__ u16 W2l[F * F];
    __shared__ float scs[F], shs[F];
    int t = threadIdx.x;
    int lane = t & 63, w = t >> 6;
    int m16 = lane & 15, quad = lane >> 4;
    for (int i = t; i < F * F; i += TPB) W2l[i] = f2bf(W2[i]);
    if (t < F) {
        float mu = stats[t] / (float)N;
        float var = stats[F + t] / (float)N - mu * mu;
        float rs = rsqrtf(var + BN_EPS);
        float sc = rs * g[t];
        scs[t] = sc;
        shs[t] = bt[t] - mu * sc;
    }
    __syncthreads();
    int row0 = (blockIdx.x * 4 + w) * 16;
    if (row0 >= N) return;
    v8s bw[4][2];
#pragma unroll
    for (int nt = 0; nt < 4; ++nt)
#pragma unroll
        for (int kc = 0; kc < 2; ++kc)
#pragma unroll
            for (int j = 0; j < 8; ++j)
                bw[nt][kc][j] = (short)W2l[(kc * 32 + quad * 8 + j) * F + nt * 16 + m16];
    v8s a[2];
#pragma unroll
    for (int kc = 0; kc < 2; ++kc) {
        const float* yp = Yf + (size_t)(row0 + m16) * F + kc * 32 + quad * 8;
        float4 r0 = *(const float4*)yp;
        float4 r1 = *(const float4*)(yp + 4);
        float vals[8] = {r0.x, r0.y, r0.z, r0.w, r1.x, r1.y, r1.z, r1.w};
#pragma unroll
        for (int j = 0; j < 8; ++j) {
            int k = kc * 32 + quad * 8 + j;
            a[kc][j] = (short)f2bf(fmaxf(vals[j] * scs[k] + shs[k], 0.f));
        }
    }
    v4f accv[4];
#pragma unroll
    for (int nt = 0; nt < 4; ++nt) {
        float bb = b2[nt * 16 + m16];
        v4f acc = {bb, bb, bb, bb};
        acc = __builtin_amdgcn_mfma_f32_16x16x32_bf16(a[0], bw[nt][0], acc, 0, 0, 0);
        acc = __builtin_amdgcn_mfma_f32_16x16x32_bf16(a[1], bw[nt][1], acc, 0, 0, 0);
        accv[nt] = acc;
    }
    int gid_prev = -1;
    float psum[4] = {0.f, 0.f, 0.f, 0.f};
#pragma unroll
    for (int reg = 0; reg < 4; ++reg) {
        int gid = batch[row0 + quad * 4 + reg];
        if (gid != gid_prev) {
            if (gid_prev >= 0)
#pragma unroll
                for (int nt = 0; nt < 4; ++nt)
                    atomicAdd(&out[(size_t)gid_prev * F + nt * 16 + m16], psum[nt]);
            gid_prev = gid;
            psum[0] = psum[1] = psum[2] = psum[3] = 0.f;
        }
#pragma unroll
        for (int nt = 0; nt < 4; ++nt) psum[nt] += accv[nt][reg];
    }
    if (gid_prev >= 0)
#pragma unroll
        for (int nt = 0; nt < 4; ++nt)
            atomicAdd(&out[(size_t)gid_prev * F + nt * 16 + m16], psum[nt]);
}

// ---- launcher -----------------------------------------------------------

extern "C" void kernel_launch(void* const* d_in, const int* in_sizes, int n_in,
                              void* d_out, int out_size, void* d_ws, size_t ws_size,
                              hipStream_t stream) {
    const float* x      = (const float*)d_in[0];
    const int*   ei     = (const int*)d_in[1];
    const int*   batch  = (const int*)d_in[2];
    const float* convW1 = (const float*)d_in[3];
    const float* convb1 = (const float*)d_in[4];
    const float* convg  = (const float*)d_in[5];
    const float* convbt = (const float*)d_in[6];
    const float* convW2 = (const float*)d_in[7];
    const float* convb2 = (const float*)d_in[8];
    const float* mlpW1  = (const float*)d_in[9];
    const float* mlpb1  = (const float*)d_in[10];
    const float* mlpg   = (const float*)d_in[11];
    const float* mlpbt  = (const float*)d_in[12];
    const float* mlpW2  = (const float*)d_in[13];
    const float* mlpb2  = (const float*)d_in[14];

    const int N = in_sizes[0] / F;             // 50000
    const int E = in_sizes[1] / 2;             // 800000
    const int L = in_sizes[3] / (F * F);       // 5

    const int* src = ei;
    const int* dst = ei + E;

    char* w = (char*)d_ws;
    size_t off = 0;
    auto alloc = [&](size_t bytes) {
        void* p = w + off;
        off = (off + bytes + 255) & ~(size_t)255;
        return p;
    };
    u16*   x16     = (u16*)alloc((size_t)N * F * 2);
    u16*   hA16    = (u16*)alloc((size_t)N * F * 2);
    u16*   hB16    = (u16*)alloc((size_t)N * F * 2);
    u16*   Ytmp16  = (u16*)alloc((size_t)N * F * 2);
    float* Yf      = (float*)alloc((size_t)N * F * 4);
    int*   deg     = (int*)alloc((size_t)N * 4);
    int*   offs    = (int*)alloc((size_t)(N + 1) * 4);
    int*   cursor  = (int*)alloc((size_t)N * 4);
    int*   csr_src = (int*)alloc((size_t)E * 4);
    int*   part    = (int*)alloc((size_t)SCAN_B * 4);
    float* stats   = (float*)alloc((size_t)(L + 1) * 128 * 4);

    hipMemsetAsync(deg, 0, (size_t)N * 4, stream);
    hipMemsetAsync(stats, 0, (size_t)(L + 1) * 128 * 4, stream);
    hipMemsetAsync(d_out, 0, (size_t)out_size * 4, stream);

    const int edgeBlocks = (E + TPB - 1) / TPB;

    k_hist<<<edgeBlocks, TPB, 0, stream>>>(dst, deg, E);
    k_scan_part<<<SCAN_B, TPB, 0, stream>>>(deg, part, N);
    k_scan_apply<<<SCAN_B, TPB, 0, stream>>>(deg, part, offs, cursor, N);
    k_fill<<<edgeBlocks, TPB, 0, stream>>>(src, dst, cursor, csr_src, E);

    const int blocksA = (N + 15) / 16;         // 3125 (16 nodes/block)
    const int blocksB = (N + 63) / 64;         // MFMA tiles

    k_prep<<<blocksB, TPB, 0, stream>>>(x, x16, mlpW1, mlpb1, Yf, N);

    const u16* h_cur = x16;
    for (int l = 0; l < L; ++l) {
        u16* h_next = (l & 1) ? hB16 : hA16;
        k_gather_gemm<<<blocksA, TPB, 0, stream>>>(h_cur, offs, csr_src,
                                                   convW1 + l * F * F, convb1 + l * F,
                                                   Ytmp16, stats + l * 128, N);
        k_layerB<<<blocksB, TPB, 0, stream>>>(Ytmp16, stats + l * 128,
                                              convg + l * F, convbt + l * F,
                                              convW2 + l * F * F, convb2 + l * F,
                                              mlpW1 + (l + 1) * F * F,
                                              h_next, Yf, stats + L * 128,
                                              N, l == L - 1);
        h_cur = h_next;
    }

    k_final<<<blocksB, TPB, 0, stream>>>(Yf, stats + L * 128, mlpg, mlpbt,
                                         mlpW2, mlpb2, batch, (float*)d_out, N);
}

// Round 4
// 560.813 us; speedup vs baseline: 1.3151x; 1.3151x over previous
//
#include <hip/hip_runtime.h>

#define F 64
#define TPB 256
#define SCAN_B 64
#define BN_EPS 1e-5f
#define NPW 8

typedef unsigned short u16;
typedef __attribute__((ext_vector_type(8))) short v8s;
typedef __attribute__((ext_vector_type(4))) float v4f;

__device__ __forceinline__ float lane_bcast(float v, int l) {
    return __int_as_float(__builtin_amdgcn_readlane(__float_as_int(v), l));
}
__device__ __forceinline__ int lane_bcast_i(int v, int l) {
    return __builtin_amdgcn_readlane(v, l);
}
__device__ __forceinline__ float bf2f(u16 u) {
    return __uint_as_float(((unsigned int)u) << 16);
}
__device__ __forceinline__ u16 f2bf(float f) {
    unsigned int u = __float_as_uint(f);
    unsigned int r = (u + 0x7fffu + ((u >> 16) & 1u)) >> 16;   // RNE
    return (u16)r;
}

// ---- CSR build ----------------------------------------------------------

__global__ __launch_bounds__(TPB) void k_hist(const int* __restrict__ dst,
                                              int* __restrict__ deg, int E) {
    int e = blockIdx.x * blockDim.x + threadIdx.x;
    if (e < E) atomicAdd(&deg[dst[e]], 1);
}

__global__ __launch_bounds__(TPB) void k_scan_part(const int* __restrict__ deg,
                                                   int* __restrict__ part, int N) {
    __shared__ int red[TPB];
    int chunk = (N + SCAN_B - 1) / SCAN_B;
    int lo = blockIdx.x * chunk, hi = min(lo + chunk, N);
    int t = threadIdx.x;
    int s = 0;
    for (int i = lo + t; i < hi; i += TPB) s += deg[i];
    red[t] = s; __syncthreads();
    for (int d = TPB / 2; d > 0; d >>= 1) {
        if (t < d) red[t] += red[t + d];
        __syncthreads();
    }
    if (t == 0) part[blockIdx.x] = red[0];
}

__global__ __launch_bounds__(TPB) void k_scan_apply(const int* __restrict__ deg,
                                                    const int* __restrict__ part,
                                                    int* __restrict__ offs,
                                                    int* __restrict__ cursor, int N) {
    __shared__ int ts[TPB];
    __shared__ int pb_s;
    int t = threadIdx.x;
    ts[t] = (t < blockIdx.x) ? part[t] : 0;
    __syncthreads();
    for (int d = TPB / 2; d > 0; d >>= 1) {
        if (t < d) ts[t] += ts[t + d];
        __syncthreads();
    }
    if (t == 0) pb_s = ts[0];
    __syncthreads();
    int pbase = pb_s;
    __syncthreads();
    int chunk = (N + SCAN_B - 1) / SCAN_B;
    int sub = (chunk + TPB - 1) / TPB;
    int lo = blockIdx.x * chunk;
    int blockhi = min(lo + chunk, N);
    int mylo = min(lo + t * sub, blockhi);
    int myhi = min(mylo + sub, blockhi);
    int s = 0;
    for (int i = mylo; i < myhi; ++i) s += deg[i];
    ts[t] = s; __syncthreads();
    for (int d = 1; d < TPB; d <<= 1) {
        int a = (t >= d) ? ts[t - d] : 0;
        __syncthreads();
        ts[t] += a;
        __syncthreads();
    }
    int run = pbase + ts[t] - s;
    for (int i = mylo; i < myhi; ++i) {
        offs[i] = run; cursor[i] = run; run += deg[i];
    }
    if (blockIdx.x == SCAN_B - 1 && t == TPB - 1) offs[N] = pbase + ts[TPB - 1];
}

__global__ __launch_bounds__(TPB) void k_fill(const int* __restrict__ src,
                                              const int* __restrict__ dst,
                                              int* __restrict__ cursor,
                                              int* __restrict__ csr_src, int E) {
    int e = blockIdx.x * blockDim.x + threadIdx.x;
    if (e >= E) return;
    int pos = atomicAdd(&cursor[dst[e]], 1);
    csr_src[pos] = src[e];
}

// ---- one-shot W1 transpose to bf16: Wt[l][n*F + k] = W[l][k*F + n] ------
__global__ __launch_bounds__(TPB) void k_wprep(const float* __restrict__ W,
                                               u16* __restrict__ Wt) {
    const float* Ws = W + (size_t)blockIdx.x * F * F;
    u16* Wd = Wt + (size_t)blockIdx.x * F * F;
    for (int i = threadIdx.x; i < F * F; i += TPB) {
        int k = i >> 6, n = i & (F - 1);
        Wd[n * F + k] = f2bf(Ws[i]);
    }
}

// ---- MFMA prep: x16 = bf16(x); Yf = x @ Wj + bias; zero pad row N -------
__global__ __launch_bounds__(TPB, 4)
void k_prep(const float* __restrict__ x, u16* __restrict__ x16,
            const float* __restrict__ Wj, const float* __restrict__ bias,
            float* __restrict__ Yf, u16* __restrict__ hA, u16* __restrict__ hB,
            int N) {
    __shared__ u16 Wjl[F * F];
    int t = threadIdx.x;
    int lane = t & 63, w = t >> 6;
    int m16 = lane & 15, quad = lane >> 4;
    for (int i = t; i < F * F; i += TPB) Wjl[i] = f2bf(Wj[i]);
    if (blockIdx.x == 0 && t < F) {          // zero pad row N (gather pad target)
        x16[(size_t)N * F + t] = 0;
        hA[(size_t)N * F + t] = 0;
        hB[(size_t)N * F + t] = 0;
    }
    __syncthreads();
    int row0 = (blockIdx.x * 4 + w) * 16;
    if (row0 >= N) return;
    v8s bfj[4][2];
#pragma unroll
    for (int nt = 0; nt < 4; ++nt)
#pragma unroll
        for (int kc = 0; kc < 2; ++kc)
#pragma unroll
            for (int j = 0; j < 8; ++j)
                bfj[nt][kc][j] = (short)Wjl[(kc * 32 + quad * 8 + j) * F + nt * 16 + m16];
    v8s a[2];
#pragma unroll
    for (int kc = 0; kc < 2; ++kc) {
        const float* xp = x + (size_t)(row0 + m16) * F + kc * 32 + quad * 8;
        float4 r0 = *(const float4*)xp;
        float4 r1 = *(const float4*)(xp + 4);
        u16 b[8] = {f2bf(r0.x), f2bf(r0.y), f2bf(r0.z), f2bf(r0.w),
                    f2bf(r1.x), f2bf(r1.y), f2bf(r1.z), f2bf(r1.w)};
#pragma unroll
        for (int j = 0; j < 8; ++j) a[kc][j] = (short)b[j];
        *(uint4*)(x16 + (size_t)(row0 + m16) * F + kc * 32 + quad * 8) = *(const uint4*)b;
    }
#pragma unroll
    for (int nt = 0; nt < 4; ++nt) {
        float bb = bias[nt * 16 + m16];
        v4f acc = {bb, bb, bb, bb};
        acc = __builtin_amdgcn_mfma_f32_16x16x32_bf16(a[0], bfj[nt][0], acc, 0, 0, 0);
        acc = __builtin_amdgcn_mfma_f32_16x16x32_bf16(a[1], bfj[nt][1], acc, 0, 0, 0);
#pragma unroll
        for (int reg = 0; reg < 4; ++reg)
            Yf[(size_t)(row0 + quad * 4 + reg) * F + nt * 16 + m16] = acc[reg];
    }
}

// ---- fused gather + MFMA GEMM1 + BN stats -------------------------------
// R0 geometry (NPW=8, 32 nodes/block, 1563 blocks) + two changes:
//  1. padded 16-batches: invalid lanes index the zeroed row N, so the
//     4-deep/1-deep remainder loops (3+ serial L2/L3 round-trips per node)
//     are gone; adds contribute 0, no masking.
//  2. W pre-transposed to bf16 in global (k_wprep): B-fragments are two
//     direct v8s loads, no per-block LDS staging / bank conflicts.
#define HPAD 72   // hb row stride in u16 (16B-aligned)

__global__ __launch_bounds__(TPB, 8)
void k_gather_gemm(const u16* __restrict__ h, const int* __restrict__ offs,
                   const int* __restrict__ csr,
                   const u16* __restrict__ Wt, const float* __restrict__ bias,
                   u16* __restrict__ Y16, float* __restrict__ stats, int N) {
    __shared__ u16 hb[32 * HPAD];     // gathered agg rows, bf16
    __shared__ float cred[2 * F];
    int t = threadIdx.x;
    int lane = t & 63, w = t >> 6;
    int m16 = lane & 15, quad = lane >> 4;
    if (t < 2 * F) cred[t] = 0.f;

    int node0 = (blockIdx.x * 4 + w) * NPW;
    int off_l = 0;
    if (lane <= NPW) off_l = offs[min(node0 + lane, N)];
    int start_n = lane_bcast_i(off_l, 0);
    int end_n   = lane_bcast_i(off_l, 1);
    int cnt_n   = min(end_n - start_n, 64);
    int idx_n   = (lane < cnt_n) ? csr[start_n + lane] : N;   // pad -> zero row
    for (int r = 0; r < NPW; ++r) {
        int node = node0 + r;
        int start = start_n, end = end_n, cnt = cnt_n, idx = idx_n;
        if (r + 1 < NPW) {
            start_n = lane_bcast_i(off_l, r + 1);
            end_n   = lane_bcast_i(off_l, r + 2);
            cnt_n   = min(end_n - start_n, 64);
            idx_n   = (lane < cnt_n) ? csr[start_n + lane] : N;
        }
        if (node >= N) { hb[(w * NPW + r) * HPAD + lane] = 0; continue; }
        float agg = bf2f(h[(size_t)node * F + lane]);    // GIN self term (eps=0)
        for (int k = 0; k < cnt; k += 16) {              // padded 16-batches
            float vv[16];
#pragma unroll
            for (int u = 0; u < 16; ++u)
                vv[u] = bf2f(h[(size_t)lane_bcast_i(idx, k + u) * F + lane]);
            float sA = 0.f, sB = 0.f, sC = 0.f, sD = 0.f;
#pragma unroll
            for (int u = 0; u < 4; ++u) {
                sA += vv[u]; sB += vv[4 + u]; sC += vv[8 + u]; sD += vv[12 + u];
            }
            agg += (sA + sB) + (sC + sD);
        }
        for (int base = start + 64; base < end; base += 64) {   // deg>64 (rare)
            int c2 = end - base; if (c2 > 64) c2 = 64;
            int idx2 = (lane < c2) ? csr[base + lane] : N;
            for (int k = 0; k < c2; k += 16) {
                float vv[16];
#pragma unroll
                for (int u = 0; u < 16; ++u)
                    vv[u] = bf2f(h[(size_t)lane_bcast_i(idx2, k + u) * F + lane]);
                float sA = 0.f, sB = 0.f, sC = 0.f, sD = 0.f;
#pragma unroll
                for (int u = 0; u < 4; ++u) {
                    sA += vv[u]; sB += vv[4 + u]; sC += vv[8 + u]; sD += vv[12 + u];
                }
                agg += (sA + sB) + (sC + sD);
            }
        }
        hb[(w * NPW + r) * HPAD + lane] = f2bf(agg);
    }
    __syncthreads();

    // MFMA phase: wave (rt = w&1, ch = w>>1) -> rows rt*16..+15, cols ch*32..+31
    int rt = w & 1, ch = w >> 1;
    int rowbase = blockIdx.x * 32 + rt * 16;
    v8s a0 = *(const v8s*)(hb + (rt * 16 + m16) * HPAD + quad * 8);
    v8s a1 = *(const v8s*)(hb + (rt * 16 + m16) * HPAD + 32 + quad * 8);
#pragma unroll
    for (int nt = 0; nt < 2; ++nt) {
        int col = ch * 32 + nt * 16 + m16;
        v8s b0 = *(const v8s*)(Wt + (size_t)col * F + quad * 8);
        v8s b1 = *(const v8s*)(Wt + (size_t)col * F + 32 + quad * 8);
        float bb = bias[col];
        v4f acc = {bb, bb, bb, bb};
        acc = __builtin_amdgcn_mfma_f32_16x16x32_bf16(a0, b0, acc, 0, 0, 0);
        acc = __builtin_amdgcn_mfma_f32_16x16x32_bf16(a1, b1, acc, 0, 0, 0);
        float ss1 = 0.f, ss2 = 0.f;
#pragma unroll
        for (int reg = 0; reg < 4; ++reg) {
            int row = rowbase + quad * 4 + reg;
            if (row < N) {
                float yv = acc[reg];
                Y16[(size_t)row * F + col] = f2bf(yv);
                ss1 += yv; ss2 += yv * yv;
            }
        }
        atomicAdd(&cred[col], ss1);
        atomicAdd(&cred[F + col], ss2);
    }
    __syncthreads();
    if (t < 2 * F) atomicAdd(&stats[t], cred[t]);
}

// ---- MFMA layerB (R19-verified) -----------------------------------------
__global__ __launch_bounds__(TPB, 3)
void k_layerB(const u16* __restrict__ Y16, const float* __restrict__ stats,
              const float* __restrict__ g, const float* __restrict__ bt,
              const float* __restrict__ W2, const float* __restrict__ b2,
              const float* __restrict__ Wj,
              u16* __restrict__ Hout, float* __restrict__ Yf,
              float* __restrict__ stats5, int N, int doHead) {
    __shared__ u16 W2l[F * F];
    __shared__ u16 Wjl[F * F];
    __shared__ float scs[F], shs[F];
    __shared__ u16 hbuf[4][16 * F];
    __shared__ float cred1[F], cred2[F];
    int t = threadIdx.x;
    int lane = t & 63, w = t >> 6;
    int m16 = lane & 15, quad = lane >> 4;
    for (int i = t; i < F * F; i += TPB) {
        W2l[i] = f2bf(W2[i]);
        Wjl[i] = f2bf(Wj[i]);
    }
    if (t < F) {
        float mu = stats[t] / (float)N;
        float var = stats[F + t] / (float)N - mu * mu;
        float rs = rsqrtf(var + BN_EPS);
        float sc = rs * g[t];
        scs[t] = sc;
        shs[t] = bt[t] - mu * sc;
    }
    __syncthreads();

    int row0 = (blockIdx.x * 4 + w) * 16;
    float s1v[4] = {0.f, 0.f, 0.f, 0.f}, s2v[4] = {0.f, 0.f, 0.f, 0.f};
    if (row0 < N) {
        v8s bf2_[4][2], bfj_[4][2];
#pragma unroll
        for (int nt = 0; nt < 4; ++nt)
#pragma unroll
            for (int kc = 0; kc < 2; ++kc)
#pragma unroll
                for (int j = 0; j < 8; ++j) {
                    int k = kc * 32 + quad * 8 + j;
                    bf2_[nt][kc][j] = (short)W2l[k * F + nt * 16 + m16];
                    bfj_[nt][kc][j] = (short)Wjl[k * F + nt * 16 + m16];
                }
        v8s a1[2];
#pragma unroll
        for (int kc = 0; kc < 2; ++kc) {
            uint4 raw = *(const uint4*)(Y16 + (size_t)(row0 + m16) * F + kc * 32 + quad * 8);
            unsigned uu[4] = {raw.x, raw.y, raw.z, raw.w};
#pragma unroll
            for (int p = 0; p < 4; ++p) {
                int k0 = kc * 32 + quad * 8 + 2 * p;
                float lo = __uint_as_float(uu[p] << 16);
                float hi = __uint_as_float(uu[p] & 0xffff0000u);
                float v0 = fmaxf(lo * scs[k0] + shs[k0], 0.f);
                float v1 = fmaxf(hi * scs[k0 + 1] + shs[k0 + 1], 0.f);
                a1[kc][2 * p]     = (short)f2bf(v0);
                a1[kc][2 * p + 1] = (short)f2bf(v1);
            }
        }
        u16* hb = hbuf[w];
#pragma unroll
        for (int nt = 0; nt < 4; ++nt) {
            float bb = b2[nt * 16 + m16];
            v4f acc = {bb, bb, bb, bb};
            acc = __builtin_amdgcn_mfma_f32_16x16x32_bf16(a1[0], bf2_[nt][0], acc, 0, 0, 0);
            acc = __builtin_amdgcn_mfma_f32_16x16x32_bf16(a1[1], bf2_[nt][1], acc, 0, 0, 0);
#pragma unroll
            for (int reg = 0; reg < 4; ++reg)
                hb[(quad * 4 + reg) * F + nt * 16 + m16] = f2bf(fmaxf(acc[reg], 0.f));
        }
#pragma unroll
        for (int rr = 0; rr < 4; ++rr) {
            int row = rr * 4 + quad;
            uint2 d = *(const uint2*)(hb + row * F + m16 * 4);
            *(uint2*)(Hout + (size_t)(row0 + row) * F + m16 * 4) = d;
        }
        v8s a2[2];
#pragma unroll
        for (int kc = 0; kc < 2; ++kc)
            a2[kc] = *(const v8s*)(hb + m16 * F + kc * 32 + quad * 8);
#pragma unroll
        for (int nt = 0; nt < 4; ++nt) {
            v4f acc;
#pragma unroll
            for (int reg = 0; reg < 4; ++reg)
                acc[reg] = Yf[(size_t)(row0 + quad * 4 + reg) * F + nt * 16 + m16];
            acc = __builtin_amdgcn_mfma_f32_16x16x32_bf16(a2[0], bfj_[nt][0], acc, 0, 0, 0);
            acc = __builtin_amdgcn_mfma_f32_16x16x32_bf16(a2[1], bfj_[nt][1], acc, 0, 0, 0);
            float ss1 = 0.f, ss2 = 0.f;
#pragma unroll
            for (int reg = 0; reg < 4; ++reg) {
                float yv = acc[reg];
                Yf[(size_t)(row0 + quad * 4 + reg) * F + nt * 16 + m16] = yv;
                ss1 += yv;
                ss2 += yv * yv;
            }
            s1v[nt] = ss1;
            s2v[nt] = ss2;
        }
    }
    if (doHead) {
        if (t < F) { cred1[t] = 0.f; cred2[t] = 0.f; }
        __syncthreads();
        if (row0 < N) {
#pragma unroll
            for (int nt = 0; nt < 4; ++nt) {
                atomicAdd(&cred1[nt * 16 + m16], s1v[nt]);
                atomicAdd(&cred2[nt * 16 + m16], s2v[nt]);
            }
        }
        __syncthreads();
        if (t < F) {
            atomicAdd(&stats5[t], cred1[t]);
            atomicAdd(&stats5[F + t], cred2[t]);
        }
    }
}

// ---- MFMA head: BN(Yf)+ReLU -> @mlpW2+b2 -> pooled add into out[graph] --
__global__ __launch_bounds__(TPB, 4)
void k_final(const float* __restrict__ Yf, const float* __restrict__ stats,
             const float* __restrict__ g, const float* __restrict__ bt,
             const float* __restrict__ W2, const float* __restrict__ b2,
             const int* __restrict__ batch, float* __restrict__ out, int N) {
    __shared__ u16 W2l[F * F];
    __shared__ float scs[F], shs[F];
    int t = threadIdx.x;
    int lane = t & 63, w = t >> 6;
    int m16 = lane & 15, quad = lane >> 4;
    for (int i = t; i < F * F; i += TPB) W2l[i] = f2bf(W2[i]);
    if (t < F) {
        float mu = stats[t] / (float)N;
        float var = stats[F + t] / (float)N - mu * mu;
        float rs = rsqrtf(var + BN_EPS);
        float sc = rs * g[t];
        scs[t] = sc;
        shs[t] = bt[t] - mu * sc;
    }
    __syncthreads();
    int row0 = (blockIdx.x * 4 + w) * 16;
    if (row0 >= N) return;
    v8s bw[4][2];
#pragma unroll
    for (int nt = 0; nt < 4; ++nt)
#pragma unroll
        for (int kc = 0; kc < 2; ++kc)
#pragma unroll
            for (int j = 0; j < 8; ++j)
                bw[nt][kc][j] = (short)W2l[(kc * 32 + quad * 8 + j) * F + nt * 16 + m16];
    v8s a[2];
#pragma unroll
    for (int kc = 0; kc < 2; ++kc) {
        const float* yp = Yf + (size_t)(row0 + m16) * F + kc * 32 + quad * 8;
        float4 r0 = *(const float4*)yp;
        float4 r1 = *(const float4*)(yp + 4);
        float vals[8] = {r0.x, r0.y, r0.z, r0.w, r1.x, r1.y, r1.z, r1.w};
#pragma unroll
        for (int j = 0; j < 8; ++j) {
            int k = kc * 32 + quad * 8 + j;
            a[kc][j] = (short)f2bf(fmaxf(vals[j] * scs[k] + shs[k], 0.f));
        }
    }
    v4f accv[4];
#pragma unroll
    for (int nt = 0; nt < 4; ++nt) {
        float bb = b2[nt * 16 + m16];
        v4f acc = {bb, bb, bb, bb};
        acc = __builtin_amdgcn_mfma_f32_16x16x32_bf16(a[0], bw[nt][0], acc, 0, 0, 0);
        acc = __builtin_amdgcn_mfma_f32_16x16x32_bf16(a[1], bw[nt][1], acc, 0, 0, 0);
        accv[nt] = acc;
    }
    int gid_prev = -1;
    float psum[4] = {0.f, 0.f, 0.f, 0.f};
#pragma unroll
    for (int reg = 0; reg < 4; ++reg) {
        int gid = batch[row0 + quad * 4 + reg];
        if (gid != gid_prev) {
            if (gid_prev >= 0)
#pragma unroll
                for (int nt = 0; nt < 4; ++nt)
                    atomicAdd(&out[(size_t)gid_prev * F + nt * 16 + m16], psum[nt]);
            gid_prev = gid;
            psum[0] = psum[1] = psum[2] = psum[3] = 0.f;
        }
#pragma unroll
        for (int nt = 0; nt < 4; ++nt) psum[nt] += accv[nt][reg];
    }
    if (gid_prev >= 0)
#pragma unroll
        for (int nt = 0; nt < 4; ++nt)
            atomicAdd(&out[(size_t)gid_prev * F + nt * 16 + m16], psum[nt]);
}

// ---- launcher -----------------------------------------------------------

extern "C" void kernel_launch(void* const* d_in, const int* in_sizes, int n_in,
                              void* d_out, int out_size, void* d_ws, size_t ws_size,
                              hipStream_t stream) {
    const float* x      = (const float*)d_in[0];
    const int*   ei     = (const int*)d_in[1];
    const int*   batch  = (const int*)d_in[2];
    const float* convW1 = (const float*)d_in[3];
    const float* convb1 = (const float*)d_in[4];
    const float* convg  = (const float*)d_in[5];
    const float* convbt = (const float*)d_in[6];
    const float* convW2 = (const float*)d_in[7];
    const float* convb2 = (const float*)d_in[8];
    const float* mlpW1  = (const float*)d_in[9];
    const float* mlpb1  = (const float*)d_in[10];
    const float* mlpg   = (const float*)d_in[11];
    const float* mlpbt  = (const float*)d_in[12];
    const float* mlpW2  = (const float*)d_in[13];
    const float* mlpb2  = (const float*)d_in[14];

    const int N = in_sizes[0] / F;             // 50000
    const int E = in_sizes[1] / 2;             // 800000
    const int L = in_sizes[3] / (F * F);       // 5

    const int* src = ei;
    const int* dst = ei + E;

    char* w = (char*)d_ws;
    size_t off = 0;
    auto alloc = [&](size_t bytes) {
        void* p = w + off;
        off = (off + bytes + 255) & ~(size_t)255;
        return p;
    };
    u16*   x16     = (u16*)alloc((size_t)(N + 1) * F * 2);   // +1: zero pad row
    u16*   hA16    = (u16*)alloc((size_t)(N + 1) * F * 2);
    u16*   hB16    = (u16*)alloc((size_t)(N + 1) * F * 2);
    u16*   Ytmp16  = (u16*)alloc((size_t)N * F * 2);
    float* Yf      = (float*)alloc((size_t)N * F * 4);
    int*   deg     = (int*)alloc((size_t)N * 4);
    int*   offs    = (int*)alloc((size_t)(N + 1) * 4);
    int*   cursor  = (int*)alloc((size_t)N * 4);
    int*   csr_src = (int*)alloc((size_t)E * 4);
    int*   part    = (int*)alloc((size_t)SCAN_B * 4);
    float* stats   = (float*)alloc((size_t)(L + 1) * 128 * 4);
    u16*   Wt      = (u16*)alloc((size_t)L * F * F * 2);     // pre-transposed W1s

    hipMemsetAsync(deg, 0, (size_t)N * 4, stream);
    hipMemsetAsync(stats, 0, (size_t)(L + 1) * 128 * 4, stream);
    hipMemsetAsync(d_out, 0, (size_t)out_size * 4, stream);

    const int edgeBlocks = (E + TPB - 1) / TPB;

    k_hist<<<edgeBlocks, TPB, 0, stream>>>(dst, deg, E);
    k_scan_part<<<SCAN_B, TPB, 0, stream>>>(deg, part, N);
    k_scan_apply<<<SCAN_B, TPB, 0, stream>>>(deg, part, offs, cursor, N);
    k_fill<<<edgeBlocks, TPB, 0, stream>>>(src, dst, cursor, csr_src, E);
    k_wprep<<<L, TPB, 0, stream>>>(convW1, Wt);

    const int blocksA = (N + 4 * NPW - 1) / (4 * NPW);   // 1563 (32 nodes/block)
    const int blocksB = (N + 63) / 64;                   // MFMA tiles

    k_prep<<<blocksB, TPB, 0, stream>>>(x, x16, mlpW1, mlpb1, Yf, hA16, hB16, N);

    const u16* h_cur = x16;
    for (int l = 0; l < L; ++l) {
        u16* h_next = (l & 1) ? hB16 : hA16;
        k_gather_gemm<<<blocksA, TPB, 0, stream>>>(h_cur, offs, csr_src,
                                                   Wt + (size_t)l * F * F, convb1 + l * F,
                                                   Ytmp16, stats + l * 128, N);
        k_layerB<<<blocksB, TPB, 0, stream>>>(Ytmp16, stats + l * 128,
                                              convg + l * F, convbt + l * F,
                                              convW2 + l * F * F, convb2 + l * F,
                                              mlpW1 + (l + 1) * F * F,
                                              h_next, Yf, stats + L * 128,
                                              N, l == L - 1);
        h_cur = h_next;
    }

    k_final<<<blocksB, TPB, 0, stream>>>(Yf, stats + L * 128, mlpg, mlpbt,
                                         mlpW2, mlpb2, batch, (float*)d_out, N);
}

// Round 5
// 553.811 us; speedup vs baseline: 1.3317x; 1.0126x over previous
//
#include <hip/hip_runtime.h>

#define F 64
#define TPB 256
#define SCAN_B 64
#define BN_EPS 1e-5f
#define NPW 8

typedef unsigned short u16;
typedef __attribute__((ext_vector_type(8))) short v8s;
typedef __attribute__((ext_vector_type(4))) float v4f;

__device__ __forceinline__ float lane_bcast(float v, int l) {
    return __int_as_float(__builtin_amdgcn_readlane(__float_as_int(v), l));
}
__device__ __forceinline__ int lane_bcast_i(int v, int l) {
    return __builtin_amdgcn_readlane(v, l);
}
__device__ __forceinline__ float bf2f(u16 u) {
    return __uint_as_float(((unsigned int)u) << 16);
}
__device__ __forceinline__ u16 f2bf(float f) {
    unsigned int u = __float_as_uint(f);
    unsigned int r = (u + 0x7fffu + ((u >> 16) & 1u)) >> 16;   // RNE
    return (u16)r;
}

// ---- CSR build ----------------------------------------------------------

__global__ __launch_bounds__(TPB) void k_hist(const int* __restrict__ dst,
                                              int* __restrict__ deg, int E) {
    int e = blockIdx.x * blockDim.x + threadIdx.x;
    if (e < E) atomicAdd(&deg[dst[e]], 1);
}

__global__ __launch_bounds__(TPB) void k_scan_part(const int* __restrict__ deg,
                                                   int* __restrict__ part, int N) {
    __shared__ int red[TPB];
    int chunk = (N + SCAN_B - 1) / SCAN_B;
    int lo = blockIdx.x * chunk, hi = min(lo + chunk, N);
    int t = threadIdx.x;
    int s = 0;
    for (int i = lo + t; i < hi; i += TPB) s += deg[i];
    red[t] = s; __syncthreads();
    for (int d = TPB / 2; d > 0; d >>= 1) {
        if (t < d) red[t] += red[t + d];
        __syncthreads();
    }
    if (t == 0) part[blockIdx.x] = red[0];
}

__global__ __launch_bounds__(TPB) void k_scan_apply(const int* __restrict__ deg,
                                                    const int* __restrict__ part,
                                                    int* __restrict__ offs,
                                                    int* __restrict__ cursor, int N) {
    __shared__ int ts[TPB];
    __shared__ int pb_s;
    int t = threadIdx.x;
    ts[t] = (t < blockIdx.x) ? part[t] : 0;
    __syncthreads();
    for (int d = TPB / 2; d > 0; d >>= 1) {
        if (t < d) ts[t] += ts[t + d];
        __syncthreads();
    }
    if (t == 0) pb_s = ts[0];
    __syncthreads();
    int pbase = pb_s;
    __syncthreads();
    int chunk = (N + SCAN_B - 1) / SCAN_B;
    int sub = (chunk + TPB - 1) / TPB;
    int lo = blockIdx.x * chunk;
    int blockhi = min(lo + chunk, N);
    int mylo = min(lo + t * sub, blockhi);
    int myhi = min(mylo + sub, blockhi);
    int s = 0;
    for (int i = mylo; i < myhi; ++i) s += deg[i];
    ts[t] = s; __syncthreads();
    for (int d = 1; d < TPB; d <<= 1) {
        int a = (t >= d) ? ts[t - d] : 0;
        __syncthreads();
        ts[t] += a;
        __syncthreads();
    }
    int run = pbase + ts[t] - s;
    for (int i = mylo; i < myhi; ++i) {
        offs[i] = run; cursor[i] = run; run += deg[i];
    }
    if (blockIdx.x == SCAN_B - 1 && t == TPB - 1) offs[N] = pbase + ts[TPB - 1];
}

__global__ __launch_bounds__(TPB) void k_fill(const int* __restrict__ src,
                                              const int* __restrict__ dst,
                                              int* __restrict__ cursor,
                                              int* __restrict__ csr_src, int E) {
    int e = blockIdx.x * blockDim.x + threadIdx.x;
    if (e >= E) return;
    int pos = atomicAdd(&cursor[dst[e]], 1);
    csr_src[pos] = src[e];
}

// ---- one-shot W1 transpose to bf16: Wt[l][n*F + k] = W[l][k*F + n] ------
__global__ __launch_bounds__(TPB) void k_wprep(const float* __restrict__ W,
                                               u16* __restrict__ Wt) {
    const float* Ws = W + (size_t)blockIdx.x * F * F;
    u16* Wd = Wt + (size_t)blockIdx.x * F * F;
    for (int i = threadIdx.x; i < F * F; i += TPB) {
        int k = i >> 6, n = i & (F - 1);
        Wd[n * F + k] = f2bf(Ws[i]);
    }
}

// ---- MFMA prep: x16 = bf16(x); Yf = x @ Wj + bias; zero pad row N -------
__global__ __launch_bounds__(TPB, 4)
void k_prep(const float* __restrict__ x, u16* __restrict__ x16,
            const float* __restrict__ Wj, const float* __restrict__ bias,
            float* __restrict__ Yf, u16* __restrict__ hA, u16* __restrict__ hB,
            int N) {
    __shared__ u16 Wjl[F * F];
    int t = threadIdx.x;
    int lane = t & 63, w = t >> 6;
    int m16 = lane & 15, quad = lane >> 4;
    for (int i = t; i < F * F; i += TPB) Wjl[i] = f2bf(Wj[i]);
    if (blockIdx.x == 0 && t < F) {          // zero pad row N (gather pad target)
        x16[(size_t)N * F + t] = 0;
        hA[(size_t)N * F + t] = 0;
        hB[(size_t)N * F + t] = 0;
    }
    __syncthreads();
    int row0 = (blockIdx.x * 4 + w) * 16;
    if (row0 >= N) return;
    v8s bfj[4][2];
#pragma unroll
    for (int nt = 0; nt < 4; ++nt)
#pragma unroll
        for (int kc = 0; kc < 2; ++kc)
#pragma unroll
            for (int j = 0; j < 8; ++j)
                bfj[nt][kc][j] = (short)Wjl[(kc * 32 + quad * 8 + j) * F + nt * 16 + m16];
    v8s a[2];
#pragma unroll
    for (int kc = 0; kc < 2; ++kc) {
        const float* xp = x + (size_t)(row0 + m16) * F + kc * 32 + quad * 8;
        float4 r0 = *(const float4*)xp;
        float4 r1 = *(const float4*)(xp + 4);
        u16 b[8] = {f2bf(r0.x), f2bf(r0.y), f2bf(r0.z), f2bf(r0.w),
                    f2bf(r1.x), f2bf(r1.y), f2bf(r1.z), f2bf(r1.w)};
#pragma unroll
        for (int j = 0; j < 8; ++j) a[kc][j] = (short)b[j];
        *(uint4*)(x16 + (size_t)(row0 + m16) * F + kc * 32 + quad * 8) = *(const uint4*)b;
    }
#pragma unroll
    for (int nt = 0; nt < 4; ++nt) {
        float bb = bias[nt * 16 + m16];
        v4f acc = {bb, bb, bb, bb};
        acc = __builtin_amdgcn_mfma_f32_16x16x32_bf16(a[0], bfj[nt][0], acc, 0, 0, 0);
        acc = __builtin_amdgcn_mfma_f32_16x16x32_bf16(a[1], bfj[nt][1], acc, 0, 0, 0);
#pragma unroll
        for (int reg = 0; reg < 4; ++reg)
            Yf[(size_t)(row0 + quad * 4 + reg) * F + nt * 16 + m16] = acc[reg];
    }
}

// ---- fused gather + MFMA GEMM1 + BN stats -------------------------------
// R4 structure + pair-deep software pipeline: issue node A's and node B's
// padded 16-batches (32 loads in flight), prefetch the NEXT pair's csr
// indices + both self rows into the same latency window, then consume.
// Exposed L2/L3 round-trips per wave: ~9.6 -> ~5.6.
#define HPAD 72   // hb row stride in u16 (16B-aligned)

#define ISSUE16(BUF, IDX, K)                                                  \
    {                                                                         \
        _Pragma("unroll")                                                     \
        for (int u_ = 0; u_ < 16; ++u_) {                                     \
            int row_ = lane_bcast_i(IDX, (K) + u_);                           \
            BUF[u_] = h[(size_t)row_ * F + lane];                             \
        }                                                                     \
    }

#define CONSUME16(BUF, AGG)                                                   \
    {                                                                         \
        float sA_ = 0.f, sB_ = 0.f, sC_ = 0.f, sD_ = 0.f;                     \
        _Pragma("unroll")                                                     \
        for (int u_ = 0; u_ < 4; ++u_) {                                      \
            sA_ += bf2f(BUF[u_]);      sB_ += bf2f(BUF[4 + u_]);              \
            sC_ += bf2f(BUF[8 + u_]);  sD_ += bf2f(BUF[12 + u_]);             \
        }                                                                     \
        AGG += (sA_ + sB_) + (sC_ + sD_);                                     \
    }

__global__ __launch_bounds__(TPB, 8)
void k_gather_gemm(const u16* __restrict__ h, const int* __restrict__ offs,
                   const int* __restrict__ csr,
                   const u16* __restrict__ Wt, const float* __restrict__ bias,
                   u16* __restrict__ Y16, float* __restrict__ stats, int N) {
    __shared__ u16 hb[32 * HPAD];     // gathered agg rows, bf16
    __shared__ float cred[2 * F];
    int t = threadIdx.x;
    int lane = t & 63, w = t >> 6;
    int m16 = lane & 15, quad = lane >> 4;
    if (t < 2 * F) cred[t] = 0.f;

    int node0 = (blockIdx.x * 4 + w) * NPW;
    int off_l = 0;
    if (lane <= NPW) off_l = offs[min(node0 + lane, N)];

    u16 bufA[16], bufB[16];
    // pair 0 boundaries + idx preload
    int sA = lane_bcast_i(off_l, 0), sB = lane_bcast_i(off_l, 1);
    int eA = sB,                     eB = lane_bcast_i(off_l, 2);
    int cA = min(eA - sA, 64),       cB = min(eB - sB, 64);
    int idxA = (lane < cA) ? csr[sA + lane] : N;
    int idxB = (lane < cB) ? csr[sB + lane] : N;

    for (int rp = 0; rp < NPW; rp += 2) {
        // issue both nodes' first padded batch (32 loads in flight)
        ISSUE16(bufA, idxA, 0);
        ISSUE16(bufB, idxB, 0);
        // save current-pair state for tails
        int idxAc = idxA, idxBc = idxB;
        int cAc = cA, cBc = cB, sAc = sA, sBc = sB, eAc = eA, eBc = eB;
        // prefetch next pair's boundaries + idx (same latency window)
        if (rp + 2 < NPW) {
            sA = lane_bcast_i(off_l, rp + 2); sB = lane_bcast_i(off_l, rp + 3);
            eA = sB;                          eB = lane_bcast_i(off_l, rp + 4);
            cA = min(eA - sA, 64);            cB = min(eB - sB, 64);
            idxA = (lane < cA) ? csr[sA + lane] : N;
            idxB = (lane < cB) ? csr[sB + lane] : N;
        }
        // self terms (GIN eps=0), also in window; node>=N hits zero pad row
        int nodeA = node0 + rp, nodeB = node0 + rp + 1;
        float aggA = bf2f(h[(size_t)min(nodeA, N) * F + lane]);
        float aggB = bf2f(h[(size_t)min(nodeB, N) * F + lane]);
        // consume A, then serial tails (deg>16: ~20% of nodes)
        CONSUME16(bufA, aggA);
        for (int k = 16; k < cAc; k += 16) {
            ISSUE16(bufA, idxAc, k); CONSUME16(bufA, aggA);
        }
        for (int base = sAc + 64; base < eAc; base += 64) {   // deg>64 (rare)
            int c2 = min(eAc - base, 64);
            int idx2 = (lane < c2) ? csr[base + lane] : N;
            for (int k = 0; k < c2; k += 16) {
                ISSUE16(bufA, idx2, k); CONSUME16(bufA, aggA);
            }
        }
        // consume B + tails
        CONSUME16(bufB, aggB);
        for (int k = 16; k < cBc; k += 16) {
            ISSUE16(bufB, idxBc, k); CONSUME16(bufB, aggB);
        }
        for (int base = sBc + 64; base < eBc; base += 64) {
            int c2 = min(eBc - base, 64);
            int idx2 = (lane < c2) ? csr[base + lane] : N;
            for (int k = 0; k < c2; k += 16) {
                ISSUE16(bufB, idx2, k); CONSUME16(bufB, aggB);
            }
        }
        hb[(w * NPW + rp) * HPAD + lane]     = f2bf(aggA);
        hb[(w * NPW + rp + 1) * HPAD + lane] = f2bf(aggB);
    }
    __syncthreads();

    // MFMA phase: wave (rt = w&1, ch = w>>1) -> rows rt*16..+15, cols ch*32..+31
    int rt = w & 1, ch = w >> 1;
    int rowbase = blockIdx.x * 32 + rt * 16;
    v8s a0 = *(const v8s*)(hb + (rt * 16 + m16) * HPAD + quad * 8);
    v8s a1 = *(const v8s*)(hb + (rt * 16 + m16) * HPAD + 32 + quad * 8);
#pragma unroll
    for (int nt = 0; nt < 2; ++nt) {
        int col = ch * 32 + nt * 16 + m16;
        v8s b0 = *(const v8s*)(Wt + (size_t)col * F + quad * 8);
        v8s b1 = *(const v8s*)(Wt + (size_t)col * F + 32 + quad * 8);
        float bb = bias[col];
        v4f acc = {bb, bb, bb, bb};
        acc = __builtin_amdgcn_mfma_f32_16x16x32_bf16(a0, b0, acc, 0, 0, 0);
        acc = __builtin_amdgcn_mfma_f32_16x16x32_bf16(a1, b1, acc, 0, 0, 0);
        float ss1 = 0.f, ss2 = 0.f;
#pragma unroll
        for (int reg = 0; reg < 4; ++reg) {
            int row = rowbase + quad * 4 + reg;
            if (row < N) {
                float yv = acc[reg];
                Y16[(size_t)row * F + col] = f2bf(yv);
                ss1 += yv; ss2 += yv * yv;
            }
        }
        atomicAdd(&cred[col], ss1);
        atomicAdd(&cred[F + col], ss2);
    }
    __syncthreads();
    if (t < 2 * F) atomicAdd(&stats[t], cred[t]);
}

// ---- MFMA layerB (R19-verified) -----------------------------------------
__global__ __launch_bounds__(TPB, 3)
void k_layerB(const u16* __restrict__ Y16, const float* __restrict__ stats,
              const float* __restrict__ g, const float* __restrict__ bt,
              const float* __restrict__ W2, const float* __restrict__ b2,
              const float* __restrict__ Wj,
              u16* __restrict__ Hout, float* __restrict__ Yf,
              float* __restrict__ stats5, int N, int doHead) {
    __shared__ u16 W2l[F * F];
    __shared__ u16 Wjl[F * F];
    __shared__ float scs[F], shs[F];
    __shared__ u16 hbuf[4][16 * F];
    __shared__ float cred1[F], cred2[F];
    int t = threadIdx.x;
    int lane = t & 63, w = t >> 6;
    int m16 = lane & 15, quad = lane >> 4;
    for (int i = t; i < F * F; i += TPB) {
        W2l[i] = f2bf(W2[i]);
        Wjl[i] = f2bf(Wj[i]);
    }
    if (t < F) {
        float mu = stats[t] / (float)N;
        float var = stats[F + t] / (float)N - mu * mu;
        float rs = rsqrtf(var + BN_EPS);
        float sc = rs * g[t];
        scs[t] = sc;
        shs[t] = bt[t] - mu * sc;
    }
    __syncthreads();

    int row0 = (blockIdx.x * 4 + w) * 16;
    float s1v[4] = {0.f, 0.f, 0.f, 0.f}, s2v[4] = {0.f, 0.f, 0.f, 0.f};
    if (row0 < N) {
        v8s bf2_[4][2], bfj_[4][2];
#pragma unroll
        for (int nt = 0; nt < 4; ++nt)
#pragma unroll
            for (int kc = 0; kc < 2; ++kc)
#pragma unroll
                for (int j = 0; j < 8; ++j) {
                    int k = kc * 32 + quad * 8 + j;
                    bf2_[nt][kc][j] = (short)W2l[k * F + nt * 16 + m16];
                    bfj_[nt][kc][j] = (short)Wjl[k * F + nt * 16 + m16];
                }
        v8s a1[2];
#pragma unroll
        for (int kc = 0; kc < 2; ++kc) {
            uint4 raw = *(const uint4*)(Y16 + (size_t)(row0 + m16) * F + kc * 32 + quad * 8);
            unsigned uu[4] = {raw.x, raw.y, raw.z, raw.w};
#pragma unroll
            for (int p = 0; p < 4; ++p) {
                int k0 = kc * 32 + quad * 8 + 2 * p;
                float lo = __uint_as_float(uu[p] << 16);
                float hi = __uint_as_float(uu[p] & 0xffff0000u);
                float v0 = fmaxf(lo * scs[k0] + shs[k0], 0.f);
                float v1 = fmaxf(hi * scs[k0 + 1] + shs[k0 + 1], 0.f);
                a1[kc][2 * p]     = (short)f2bf(v0);
                a1[kc][2 * p + 1] = (short)f2bf(v1);
            }
        }
        u16* hb = hbuf[w];
#pragma unroll
        for (int nt = 0; nt < 4; ++nt) {
            float bb = b2[nt * 16 + m16];
            v4f acc = {bb, bb, bb, bb};
            acc = __builtin_amdgcn_mfma_f32_16x16x32_bf16(a1[0], bf2_[nt][0], acc, 0, 0, 0);
            acc = __builtin_amdgcn_mfma_f32_16x16x32_bf16(a1[1], bf2_[nt][1], acc, 0, 0, 0);
#pragma unroll
            for (int reg = 0; reg < 4; ++reg)
                hb[(quad * 4 + reg) * F + nt * 16 + m16] = f2bf(fmaxf(acc[reg], 0.f));
        }
#pragma unroll
        for (int rr = 0; rr < 4; ++rr) {
            int row = rr * 4 + quad;
            uint2 d = *(const uint2*)(hb + row * F + m16 * 4);
            *(uint2*)(Hout + (size_t)(row0 + row) * F + m16 * 4) = d;
        }
        v8s a2[2];
#pragma unroll
        for (int kc = 0; kc < 2; ++kc)
            a2[kc] = *(const v8s*)(hb + m16 * F + kc * 32 + quad * 8);
#pragma unroll
        for (int nt = 0; nt < 4; ++nt) {
            v4f acc;
#pragma unroll
            for (int reg = 0; reg < 4; ++reg)
                acc[reg] = Yf[(size_t)(row0 + quad * 4 + reg) * F + nt * 16 + m16];
            acc = __builtin_amdgcn_mfma_f32_16x16x32_bf16(a2[0], bfj_[nt][0], acc, 0, 0, 0);
            acc = __builtin_amdgcn_mfma_f32_16x16x32_bf16(a2[1], bfj_[nt][1], acc, 0, 0, 0);
            float ss1 = 0.f, ss2 = 0.f;
#pragma unroll
            for (int reg = 0; reg < 4; ++reg) {
                float yv = acc[reg];
                Yf[(size_t)(row0 + quad * 4 + reg) * F + nt * 16 + m16] = yv;
                ss1 += yv;
                ss2 += yv * yv;
            }
            s1v[nt] = ss1;
            s2v[nt] = ss2;
        }
    }
    if (doHead) {
        if (t < F) { cred1[t] = 0.f; cred2[t] = 0.f; }
        __syncthreads();
        if (row0 < N) {
#pragma unroll
            for (int nt = 0; nt < 4; ++nt) {
                atomicAdd(&cred1[nt * 16 + m16], s1v[nt]);
                atomicAdd(&cred2[nt * 16 + m16], s2v[nt]);
            }
        }
        __syncthreads();
        if (t < F) {
            atomicAdd(&stats5[t], cred1[t]);
            atomicAdd(&stats5[F + t], cred2[t]);
        }
    }
}

// ---- MFMA head: BN(Yf)+ReLU -> @mlpW2+b2 -> pooled add into out[graph] --
__global__ __launch_bounds__(TPB, 4)
void k_final(const float* __restrict__ Yf, const float* __restrict__ stats,
             const float* __restrict__ g, const float* __restrict__ bt,
             const float* __restrict__ W2, const float* __restrict__ b2,
             const int* __restrict__ batch, float* __restrict__ out, int N) {
    __shared__ u16 W2l[F * F];
    __shared__ float scs[F], shs[F];
    int t = threadIdx.x;
    int lane = t & 63, w = t >> 6;
    int m16 = lane & 15, quad = lane >> 4;
    for (int i = t; i < F * F; i += TPB) W2l[i] = f2bf(W2[i]);
    if (t < F) {
        float mu = stats[t] / (float)N;
        float var = stats[F + t] / (float)N - mu * mu;
        float rs = rsqrtf(var + BN_EPS);
        float sc = rs * g[t];
        scs[t] = sc;
        shs[t] = bt[t] - mu * sc;
    }
    __syncthreads();
    int row0 = (blockIdx.x * 4 + w) * 16;
    if (row0 >= N) return;
    v8s bw[4][2];
#pragma unroll
    for (int nt = 0; nt < 4; ++nt)
#pragma unroll
        for (int kc = 0; kc < 2; ++kc)
#pragma unroll
            for (int j = 0; j < 8; ++j)
                bw[nt][kc][j] = (short)W2l[(kc * 32 + quad * 8 + j) * F + nt * 16 + m16];
    v8s a[2];
#pragma unroll
    for (int kc = 0; kc < 2; ++kc) {
        const float* yp = Yf + (size_t)(row0 + m16) * F + kc * 32 + quad * 8;
        float4 r0 = *(const float4*)yp;
        float4 r1 = *(const float4*)(yp + 4);
        float vals[8] = {r0.x, r0.y, r0.z, r0.w, r1.x, r1.y, r1.z, r1.w};
#pragma unroll
        for (int j = 0; j < 8; ++j) {
            int k = kc * 32 + quad * 8 + j;
            a[kc][j] = (short)f2bf(fmaxf(vals[j] * scs[k] + shs[k], 0.f));
        }
    }
    v4f accv[4];
#pragma unroll
    for (int nt = 0; nt < 4; ++nt) {
        float bb = b2[nt * 16 + m16];
        v4f acc = {bb, bb, bb, bb};
        acc = __builtin_amdgcn_mfma_f32_16x16x32_bf16(a[0], bw[nt][0], acc, 0, 0, 0);
        acc = __builtin_amdgcn_mfma_f32_16x16x32_bf16(a[1], bw[nt][1], acc, 0, 0, 0);
        accv[nt] = acc;
    }
    int gid_prev = -1;
    float psum[4] = {0.f, 0.f, 0.f, 0.f};
#pragma unroll
    for (int reg = 0; reg < 4; ++reg) {
        int gid = batch[row0 + quad * 4 + reg];
        if (gid != gid_prev) {
            if (gid_prev >= 0)
#pragma unroll
                for (int nt = 0; nt < 4; ++nt)
                    atomicAdd(&out[(size_t)gid_prev * F + nt * 16 + m16], psum[nt]);
            gid_prev = gid;
            psum[0] = psum[1] = psum[2] = psum[3] = 0.f;
        }
#pragma unroll
        for (int nt = 0; nt < 4; ++nt) psum[nt] += accv[nt][reg];
    }
    if (gid_prev >= 0)
#pragma unroll
        for (int nt = 0; nt < 4; ++nt)
            atomicAdd(&out[(size_t)gid_prev * F + nt * 16 + m16], psum[nt]);
}

// ---- launcher -----------------------------------------------------------

extern "C" void kernel_launch(void* const* d_in, const int* in_sizes, int n_in,
                              void* d_out, int out_size, void* d_ws, size_t ws_size,
                              hipStream_t stream) {
    const float* x      = (const float*)d_in[0];
    const int*   ei     = (const int*)d_in[1];
    const int*   batch  = (const int*)d_in[2];
    const float* convW1 = (const float*)d_in[3];
    const float* convb1 = (const float*)d_in[4];
    const float* convg  = (const float*)d_in[5];
    const float* convbt = (const float*)d_in[6];
    const float* convW2 = (const float*)d_in[7];
    const float* convb2 = (const float*)d_in[8];
    const float* mlpW1  = (const float*)d_in[9];
    const float* mlpb1  = (const float*)d_in[10];
    const float* mlpg   = (const float*)d_in[11];
    const float* mlpbt  = (const float*)d_in[12];
    const float* mlpW2  = (const float*)d_in[13];
    const float* mlpb2  = (const float*)d_in[14];

    const int N = in_sizes[0] / F;             // 50000
    const int E = in_sizes[1] / 2;             // 800000
    const int L = in_sizes[3] / (F * F);       // 5

    const int* src = ei;
    const int* dst = ei + E;

    char* w = (char*)d_ws;
    size_t off = 0;
    auto alloc = [&](size_t bytes) {
        void* p = w + off;
        off = (off + bytes + 255) & ~(size_t)255;
        return p;
    };
    u16*   x16     = (u16*)alloc((size_t)(N + 1) * F * 2);   // +1: zero pad row
    u16*   hA16    = (u16*)alloc((size_t)(N + 1) * F * 2);
    u16*   hB16    = (u16*)alloc((size_t)(N + 1) * F * 2);
    u16*   Ytmp16  = (u16*)alloc((size_t)N * F * 2);
    float* Yf      = (float*)alloc((size_t)N * F * 4);
    int*   deg     = (int*)alloc((size_t)N * 4);
    int*   offs    = (int*)alloc((size_t)(N + 1) * 4);
    int*   cursor  = (int*)alloc((size_t)N * 4);
    int*   csr_src = (int*)alloc((size_t)E * 4);
    int*   part    = (int*)alloc((size_t)SCAN_B * 4);
    float* stats   = (float*)alloc((size_t)(L + 1) * 128 * 4);
    u16*   Wt      = (u16*)alloc((size_t)L * F * F * 2);     // pre-transposed W1s

    hipMemsetAsync(deg, 0, (size_t)N * 4, stream);
    hipMemsetAsync(stats, 0, (size_t)(L + 1) * 128 * 4, stream);
    hipMemsetAsync(d_out, 0, (size_t)out_size * 4, stream);

    const int edgeBlocks = (E + TPB - 1) / TPB;

    k_hist<<<edgeBlocks, TPB, 0, stream>>>(dst, deg, E);
    k_scan_part<<<SCAN_B, TPB, 0, stream>>>(deg, part, N);
    k_scan_apply<<<SCAN_B, TPB, 0, stream>>>(deg, part, offs, cursor, N);
    k_fill<<<edgeBlocks, TPB, 0, stream>>>(src, dst, cursor, csr_src, E);
    k_wprep<<<L, TPB, 0, stream>>>(convW1, Wt);

    const int blocksA = (N + 4 * NPW - 1) / (4 * NPW);   // 1563 (32 nodes/block)
    const int blocksB = (N + 63) / 64;                   // MFMA tiles

    k_prep<<<blocksB, TPB, 0, stream>>>(x, x16, mlpW1, mlpb1, Yf, hA16, hB16, N);

    const u16* h_cur = x16;
    for (int l = 0; l < L; ++l) {
        u16* h_next = (l & 1) ? hB16 : hA16;
        k_gather_gemm<<<blocksA, TPB, 0, stream>>>(h_cur, offs, csr_src,
                                                   Wt + (size_t)l * F * F, convb1 + l * F,
                                                   Ytmp16, stats + l * 128, N);
        k_layerB<<<blocksB, TPB, 0, stream>>>(Ytmp16, stats + l * 128,
                                              convg + l * F, convbt + l * F,
                                              convW2 + l * F * F, convb2 + l * F,
                                              mlpW1 + (l + 1) * F * F,
                                              h_next, Yf, stats + L * 128,
                                              N, l == L - 1);
        h_cur = h_next;
    }

    k_final<<<blocksB, TPB, 0, stream>>>(Yf, stats + L * 128, mlpg, mlpbt,
                                         mlpW2, mlpb2, batch, (float*)d_out, N);
}

// Round 6
// 553.162 us; speedup vs baseline: 1.3333x; 1.0012x over previous
//
#include <hip/hip_runtime.h>

#define F 64
#define TPB 256
#define SCAN_B 64
#define BN_EPS 1e-5f
#define NPW 8

typedef unsigned short u16;
typedef __attribute__((ext_vector_type(8))) short v8s;
typedef __attribute__((ext_vector_type(4))) float v4f;

__device__ __forceinline__ float lane_bcast(float v, int l) {
    return __int_as_float(__builtin_amdgcn_readlane(__float_as_int(v), l));
}
__device__ __forceinline__ int lane_bcast_i(int v, int l) {
    return __builtin_amdgcn_readlane(v, l);
}
__device__ __forceinline__ float bf2f(u16 u) {
    return __uint_as_float(((unsigned int)u) << 16);
}
__device__ __forceinline__ u16 f2bf(float f) {
    unsigned int u = __float_as_uint(f);
    unsigned int r = (u + 0x7fffu + ((u >> 16) & 1u)) >> 16;   // RNE
    return (u16)r;
}

// ---- CSR build ----------------------------------------------------------

__global__ __launch_bounds__(TPB) void k_hist(const int* __restrict__ dst,
                                              int* __restrict__ deg, int E) {
    int e = blockIdx.x * blockDim.x + threadIdx.x;
    if (e < E) atomicAdd(&deg[dst[e]], 1);
}

__global__ __launch_bounds__(TPB) void k_scan_part(const int* __restrict__ deg,
                                                   int* __restrict__ part, int N) {
    __shared__ int red[TPB];
    int chunk = (N + SCAN_B - 1) / SCAN_B;
    int lo = blockIdx.x * chunk, hi = min(lo + chunk, N);
    int t = threadIdx.x;
    int s = 0;
    for (int i = lo + t; i < hi; i += TPB) s += deg[i];
    red[t] = s; __syncthreads();
    for (int d = TPB / 2; d > 0; d >>= 1) {
        if (t < d) red[t] += red[t + d];
        __syncthreads();
    }
    if (t == 0) part[blockIdx.x] = red[0];
}

__global__ __launch_bounds__(TPB) void k_scan_apply(const int* __restrict__ deg,
                                                    const int* __restrict__ part,
                                                    int* __restrict__ offs,
                                                    int* __restrict__ cursor, int N) {
    __shared__ int ts[TPB];
    __shared__ int pb_s;
    int t = threadIdx.x;
    ts[t] = (t < blockIdx.x) ? part[t] : 0;
    __syncthreads();
    for (int d = TPB / 2; d > 0; d >>= 1) {
        if (t < d) ts[t] += ts[t + d];
        __syncthreads();
    }
    if (t == 0) pb_s = ts[0];
    __syncthreads();
    int pbase = pb_s;
    __syncthreads();
    int chunk = (N + SCAN_B - 1) / SCAN_B;
    int sub = (chunk + TPB - 1) / TPB;
    int lo = blockIdx.x * chunk;
    int blockhi = min(lo + chunk, N);
    int mylo = min(lo + t * sub, blockhi);
    int myhi = min(mylo + sub, blockhi);
    int s = 0;
    for (int i = mylo; i < myhi; ++i) s += deg[i];
    ts[t] = s; __syncthreads();
    for (int d = 1; d < TPB; d <<= 1) {
        int a = (t >= d) ? ts[t - d] : 0;
        __syncthreads();
        ts[t] += a;
        __syncthreads();
    }
    int run = pbase + ts[t] - s;
    for (int i = mylo; i < myhi; ++i) {
        offs[i] = run; cursor[i] = run; run += deg[i];
    }
    if (blockIdx.x == SCAN_B - 1 && t == TPB - 1) offs[N] = pbase + ts[TPB - 1];
}

__global__ __launch_bounds__(TPB) void k_fill(const int* __restrict__ src,
                                              const int* __restrict__ dst,
                                              int* __restrict__ cursor,
                                              int* __restrict__ csr_src, int E) {
    int e = blockIdx.x * blockDim.x + threadIdx.x;
    if (e >= E) return;
    int pos = atomicAdd(&cursor[dst[e]], 1);
    csr_src[pos] = src[e];
}

// ---- one-shot W1 transpose to bf16: Wt[l][n*F + k] = W[l][k*F + n] ------
__global__ __launch_bounds__(TPB) void k_wprep(const float* __restrict__ W,
                                               u16* __restrict__ Wt) {
    const float* Ws = W + (size_t)blockIdx.x * F * F;
    u16* Wd = Wt + (size_t)blockIdx.x * F * F;
    for (int i = threadIdx.x; i < F * F; i += TPB) {
        int k = i >> 6, n = i & (F - 1);
        Wd[n * F + k] = f2bf(Ws[i]);
    }
}

// ---- MFMA prep: x16 = bf16(x); Yf = x @ Wj + bias; zero pad row N -------
__global__ __launch_bounds__(TPB, 4)
void k_prep(const float* __restrict__ x, u16* __restrict__ x16,
            const float* __restrict__ Wj, const float* __restrict__ bias,
            float* __restrict__ Yf, u16* __restrict__ hA, u16* __restrict__ hB,
            int N) {
    __shared__ u16 Wjl[F * F];
    int t = threadIdx.x;
    int lane = t & 63, w = t >> 6;
    int m16 = lane & 15, quad = lane >> 4;
    for (int i = t; i < F * F; i += TPB) Wjl[i] = f2bf(Wj[i]);
    if (blockIdx.x == 0 && t < F) {          // zero pad row N (gather pad target)
        x16[(size_t)N * F + t] = 0;
        hA[(size_t)N * F + t] = 0;
        hB[(size_t)N * F + t] = 0;
    }
    __syncthreads();
    int row0 = (blockIdx.x * 4 + w) * 16;
    if (row0 >= N) return;
    v8s bfj[4][2];
#pragma unroll
    for (int nt = 0; nt < 4; ++nt)
#pragma unroll
        for (int kc = 0; kc < 2; ++kc)
#pragma unroll
            for (int j = 0; j < 8; ++j)
                bfj[nt][kc][j] = (short)Wjl[(kc * 32 + quad * 8 + j) * F + nt * 16 + m16];
    v8s a[2];
#pragma unroll
    for (int kc = 0; kc < 2; ++kc) {
        const float* xp = x + (size_t)(row0 + m16) * F + kc * 32 + quad * 8;
        float4 r0 = *(const float4*)xp;
        float4 r1 = *(const float4*)(xp + 4);
        u16 b[8] = {f2bf(r0.x), f2bf(r0.y), f2bf(r0.z), f2bf(r0.w),
                    f2bf(r1.x), f2bf(r1.y), f2bf(r1.z), f2bf(r1.w)};
#pragma unroll
        for (int j = 0; j < 8; ++j) a[kc][j] = (short)b[j];
        *(uint4*)(x16 + (size_t)(row0 + m16) * F + kc * 32 + quad * 8) = *(const uint4*)b;
    }
#pragma unroll
    for (int nt = 0; nt < 4; ++nt) {
        float bb = bias[nt * 16 + m16];
        v4f acc = {bb, bb, bb, bb};
        acc = __builtin_amdgcn_mfma_f32_16x16x32_bf16(a[0], bfj[nt][0], acc, 0, 0, 0);
        acc = __builtin_amdgcn_mfma_f32_16x16x32_bf16(a[1], bfj[nt][1], acc, 0, 0, 0);
#pragma unroll
        for (int reg = 0; reg < 4; ++reg)
            Yf[(size_t)(row0 + quad * 4 + reg) * F + nt * 16 + m16] = acc[reg];
    }
}

// ---- fused gather + MFMA GEMM1 + BN stats -------------------------------
// R5 + real pipeline depth: __launch_bounds__(256,4) gives the compiler a
// 128-VGPR budget (R5's (256,8)/32-VGPR forced it to re-serialize the
// pipeline). Per node BOTH padded 16-batches are issued up front (pad lanes
// index zero row N), pair-deep across 2 nodes -> 64 loads in flight.
// Serial remainder only for deg>32 (P ~ 2e-4).
#define HPAD 72   // hb row stride in u16 (16B-aligned)

#define ISSUE16(BUF, IDX, K)                                                  \
    {                                                                         \
        _Pragma("unroll")                                                     \
        for (int u_ = 0; u_ < 16; ++u_) {                                     \
            int row_ = lane_bcast_i(IDX, (K) + u_);                           \
            BUF[u_] = h[(size_t)row_ * F + lane];                             \
        }                                                                     \
    }

#define CONSUME16(BUF, AGG)                                                   \
    {                                                                         \
        float sA_ = 0.f, sB_ = 0.f, sC_ = 0.f, sD_ = 0.f;                     \
        _Pragma("unroll")                                                     \
        for (int u_ = 0; u_ < 4; ++u_) {                                      \
            sA_ += bf2f(BUF[u_]);      sB_ += bf2f(BUF[4 + u_]);              \
            sC_ += bf2f(BUF[8 + u_]);  sD_ += bf2f(BUF[12 + u_]);             \
        }                                                                     \
        AGG += (sA_ + sB_) + (sC_ + sD_);                                     \
    }

__global__ __launch_bounds__(TPB, 4)
void k_gather_gemm(const u16* __restrict__ h, const int* __restrict__ offs,
                   const int* __restrict__ csr,
                   const u16* __restrict__ Wt, const float* __restrict__ bias,
                   u16* __restrict__ Y16, float* __restrict__ stats, int N) {
    __shared__ u16 hb[32 * HPAD];     // gathered agg rows, bf16
    __shared__ float cred[2 * F];
    int t = threadIdx.x;
    int lane = t & 63, w = t >> 6;
    int m16 = lane & 15, quad = lane >> 4;
    if (t < 2 * F) cred[t] = 0.f;

    int node0 = (blockIdx.x * 4 + w) * NPW;
    int off_l = 0;
    if (lane <= NPW) off_l = offs[min(node0 + lane, N)];

    u16 bufA0[16], bufA1[16], bufB0[16], bufB1[16];
    // pair 0 boundaries + idx preload
    int sA = lane_bcast_i(off_l, 0), sB = lane_bcast_i(off_l, 1);
    int eA = sB,                     eB = lane_bcast_i(off_l, 2);
    int cA = min(eA - sA, 64),       cB = min(eB - sB, 64);
    int idxA = (lane < cA) ? csr[sA + lane] : N;
    int idxB = (lane < cB) ? csr[sB + lane] : N;

    for (int rp = 0; rp < NPW; rp += 2) {
        // issue both nodes' two padded batches: 64 loads in flight
        ISSUE16(bufA0, idxA, 0);
        ISSUE16(bufA1, idxA, 16);
        ISSUE16(bufB0, idxB, 0);
        ISSUE16(bufB1, idxB, 16);
        // save current-pair state for rare tails
        int idxAc = idxA, idxBc = idxB;
        int cAc = cA, cBc = cB, sAc = sA, sBc = sB, eAc = eA, eBc = eB;
        // prefetch next pair's boundaries + idx (same latency window)
        if (rp + 2 < NPW) {
            sA = lane_bcast_i(off_l, rp + 2); sB = lane_bcast_i(off_l, rp + 3);
            eA = sB;                          eB = lane_bcast_i(off_l, rp + 4);
            cA = min(eA - sA, 64);            cB = min(eB - sB, 64);
            idxA = (lane < cA) ? csr[sA + lane] : N;
            idxB = (lane < cB) ? csr[sB + lane] : N;
        }
        // self terms (GIN eps=0), also in window; node>=N hits zero pad row
        int nodeA = node0 + rp, nodeB = node0 + rp + 1;
        float aggA = bf2f(h[(size_t)min(nodeA, N) * F + lane]);
        float aggB = bf2f(h[(size_t)min(nodeB, N) * F + lane]);
        // consume A (both batches), then rare serial tails (deg>32)
        CONSUME16(bufA0, aggA);
        CONSUME16(bufA1, aggA);
        for (int k = 32; k < cAc; k += 16) {
            ISSUE16(bufA0, idxAc, k); CONSUME16(bufA0, aggA);
        }
        for (int base = sAc + 64; base < eAc; base += 64) {   // deg>64 (rare)
            int c2 = min(eAc - base, 64);
            int idx2 = (lane < c2) ? csr[base + lane] : N;
            for (int k = 0; k < c2; k += 16) {
                ISSUE16(bufA0, idx2, k); CONSUME16(bufA0, aggA);
            }
        }
        // consume B + tails
        CONSUME16(bufB0, aggB);
        CONSUME16(bufB1, aggB);
        for (int k = 32; k < cBc; k += 16) {
            ISSUE16(bufB0, idxBc, k); CONSUME16(bufB0, aggB);
        }
        for (int base = sBc + 64; base < eBc; base += 64) {
            int c2 = min(eBc - base, 64);
            int idx2 = (lane < c2) ? csr[base + lane] : N;
            for (int k = 0; k < c2; k += 16) {
                ISSUE16(bufB0, idx2, k); CONSUME16(bufB0, aggB);
            }
        }
        hb[(w * NPW + rp) * HPAD + lane]     = f2bf(aggA);
        hb[(w * NPW + rp + 1) * HPAD + lane] = f2bf(aggB);
    }
    __syncthreads();

    // MFMA phase: wave (rt = w&1, ch = w>>1) -> rows rt*16..+15, cols ch*32..+31
    int rt = w & 1, ch = w >> 1;
    int rowbase = blockIdx.x * 32 + rt * 16;
    v8s a0 = *(const v8s*)(hb + (rt * 16 + m16) * HPAD + quad * 8);
    v8s a1 = *(const v8s*)(hb + (rt * 16 + m16) * HPAD + 32 + quad * 8);
#pragma unroll
    for (int nt = 0; nt < 2; ++nt) {
        int col = ch * 32 + nt * 16 + m16;
        v8s b0 = *(const v8s*)(Wt + (size_t)col * F + quad * 8);
        v8s b1 = *(const v8s*)(Wt + (size_t)col * F + 32 + quad * 8);
        float bb = bias[col];
        v4f acc = {bb, bb, bb, bb};
        acc = __builtin_amdgcn_mfma_f32_16x16x32_bf16(a0, b0, acc, 0, 0, 0);
        acc = __builtin_amdgcn_mfma_f32_16x16x32_bf16(a1, b1, acc, 0, 0, 0);
        float ss1 = 0.f, ss2 = 0.f;
#pragma unroll
        for (int reg = 0; reg < 4; ++reg) {
            int row = rowbase + quad * 4 + reg;
            if (row < N) {
                float yv = acc[reg];
                Y16[(size_t)row * F + col] = f2bf(yv);
                ss1 += yv; ss2 += yv * yv;
            }
        }
        atomicAdd(&cred[col], ss1);
        atomicAdd(&cred[F + col], ss2);
    }
    __syncthreads();
    if (t < 2 * F) atomicAdd(&stats[t], cred[t]);
}

// ---- MFMA layerB (R19-verified) -----------------------------------------
__global__ __launch_bounds__(TPB, 3)
void k_layerB(const u16* __restrict__ Y16, const float* __restrict__ stats,
              const float* __restrict__ g, const float* __restrict__ bt,
              const float* __restrict__ W2, const float* __restrict__ b2,
              const float* __restrict__ Wj,
              u16* __restrict__ Hout, float* __restrict__ Yf,
              float* __restrict__ stats5, int N, int doHead) {
    __shared__ u16 W2l[F * F];
    __shared__ u16 Wjl[F * F];
    __shared__ float scs[F], shs[F];
    __shared__ u16 hbuf[4][16 * F];
    __shared__ float cred1[F], cred2[F];
    int t = threadIdx.x;
    int lane = t & 63, w = t >> 6;
    int m16 = lane & 15, quad = lane >> 4;
    for (int i = t; i < F * F; i += TPB) {
        W2l[i] = f2bf(W2[i]);
        Wjl[i] = f2bf(Wj[i]);
    }
    if (t < F) {
        float mu = stats[t] / (float)N;
        float var = stats[F + t] / (float)N - mu * mu;
        float rs = rsqrtf(var + BN_EPS);
        float sc = rs * g[t];
        scs[t] = sc;
        shs[t] = bt[t] - mu * sc;
    }
    __syncthreads();

    int row0 = (blockIdx.x * 4 + w) * 16;
    float s1v[4] = {0.f, 0.f, 0.f, 0.f}, s2v[4] = {0.f, 0.f, 0.f, 0.f};
    if (row0 < N) {
        v8s bf2_[4][2], bfj_[4][2];
#pragma unroll
        for (int nt = 0; nt < 4; ++nt)
#pragma unroll
            for (int kc = 0; kc < 2; ++kc)
#pragma unroll
                for (int j = 0; j < 8; ++j) {
                    int k = kc * 32 + quad * 8 + j;
                    bf2_[nt][kc][j] = (short)W2l[k * F + nt * 16 + m16];
                    bfj_[nt][kc][j] = (short)Wjl[k * F + nt * 16 + m16];
                }
        v8s a1[2];
#pragma unroll
        for (int kc = 0; kc < 2; ++kc) {
            uint4 raw = *(const uint4*)(Y16 + (size_t)(row0 + m16) * F + kc * 32 + quad * 8);
            unsigned uu[4] = {raw.x, raw.y, raw.z, raw.w};
#pragma unroll
            for (int p = 0; p < 4; ++p) {
                int k0 = kc * 32 + quad * 8 + 2 * p;
                float lo = __uint_as_float(uu[p] << 16);
                float hi = __uint_as_float(uu[p] & 0xffff0000u);
                float v0 = fmaxf(lo * scs[k0] + shs[k0], 0.f);
                float v1 = fmaxf(hi * scs[k0 + 1] + shs[k0 + 1], 0.f);
                a1[kc][2 * p]     = (short)f2bf(v0);
                a1[kc][2 * p + 1] = (short)f2bf(v1);
            }
        }
        u16* hb = hbuf[w];
#pragma unroll
        for (int nt = 0; nt < 4; ++nt) {
            float bb = b2[nt * 16 + m16];
            v4f acc = {bb, bb, bb, bb};
            acc = __builtin_amdgcn_mfma_f32_16x16x32_bf16(a1[0], bf2_[nt][0], acc, 0, 0, 0);
            acc = __builtin_amdgcn_mfma_f32_16x16x32_bf16(a1[1], bf2_[nt][1], acc, 0, 0, 0);
#pragma unroll
            for (int reg = 0; reg < 4; ++reg)
                hb[(quad * 4 + reg) * F + nt * 16 + m16] = f2bf(fmaxf(acc[reg], 0.f));
        }
#pragma unroll
        for (int rr = 0; rr < 4; ++rr) {
            int row = rr * 4 + quad;
            uint2 d = *(const uint2*)(hb + row * F + m16 * 4);
            *(uint2*)(Hout + (size_t)(row0 + row) * F + m16 * 4) = d;
        }
        v8s a2[2];
#pragma unroll
        for (int kc = 0; kc < 2; ++kc)
            a2[kc] = *(const v8s*)(hb + m16 * F + kc * 32 + quad * 8);
#pragma unroll
        for (int nt = 0; nt < 4; ++nt) {
            v4f acc;
#pragma unroll
            for (int reg = 0; reg < 4; ++reg)
                acc[reg] = Yf[(size_t)(row0 + quad * 4 + reg) * F + nt * 16 + m16];
            acc = __builtin_amdgcn_mfma_f32_16x16x32_bf16(a2[0], bfj_[nt][0], acc, 0, 0, 0);
            acc = __builtin_amdgcn_mfma_f32_16x16x32_bf16(a2[1], bfj_[nt][1], acc, 0, 0, 0);
            float ss1 = 0.f, ss2 = 0.f;
#pragma unroll
            for (int reg = 0; reg < 4; ++reg) {
                float yv = acc[reg];
                Yf[(size_t)(row0 + quad * 4 + reg) * F + nt * 16 + m16] = yv;
                ss1 += yv;
                ss2 += yv * yv;
            }
            s1v[nt] = ss1;
            s2v[nt] = ss2;
        }
    }
    if (doHead) {
        if (t < F) { cred1[t] = 0.f; cred2[t] = 0.f; }
        __syncthreads();
        if (row0 < N) {
#pragma unroll
            for (int nt = 0; nt < 4; ++nt) {
                atomicAdd(&cred1[nt * 16 + m16], s1v[nt]);
                atomicAdd(&cred2[nt * 16 + m16], s2v[nt]);
            }
        }
        __syncthreads();
        if (t < F) {
            atomicAdd(&stats5[t], cred1[t]);
            atomicAdd(&stats5[F + t], cred2[t]);
        }
    }
}

// ---- MFMA head: BN(Yf)+ReLU -> @mlpW2+b2 -> pooled add into out[graph] --
__global__ __launch_bounds__(TPB, 4)
void k_final(const float* __restrict__ Yf, const float* __restrict__ stats,
             const float* __restrict__ g, const float* __restrict__ bt,
             const float* __restrict__ W2, const float* __restrict__ b2,
             const int* __restrict__ batch, float* __restrict__ out, int N) {
    __shared__ u16 W2l[F * F];
    __shared__ float scs[F], shs[F];
    int t = threadIdx.x;
    int lane = t & 63, w = t >> 6;
    int m16 = lane & 15, quad = lane >> 4;
    for (int i = t; i < F * F; i += TPB) W2l[i] = f2bf(W2[i]);
    if (t < F) {
        float mu = stats[t] / (float)N;
        float var = stats[F + t] / (float)N - mu * mu;
        float rs = rsqrtf(var + BN_EPS);
        float sc = rs * g[t];
        scs[t] = sc;
        shs[t] = bt[t] - mu * sc;
    }
    __syncthreads();
    int row0 = (blockIdx.x * 4 + w) * 16;
    if (row0 >= N) return;
    v8s bw[4][2];
#pragma unroll
    for (int nt = 0; nt < 4; ++nt)
#pragma unroll
        for (int kc = 0; kc < 2; ++kc)
#pragma unroll
            for (int j = 0; j < 8; ++j)
                bw[nt][kc][j] = (short)W2l[(kc * 32 + quad * 8 + j) * F + nt * 16 + m16];
    v8s a[2];
#pragma unroll
    for (int kc = 0; kc < 2; ++kc) {
        const float* yp = Yf + (size_t)(row0 + m16) * F + kc * 32 + quad * 8;
        float4 r0 = *(const float4*)yp;
        float4 r1 = *(const float4*)(yp + 4);
        float vals[8] = {r0.x, r0.y, r0.z, r0.w, r1.x, r1.y, r1.z, r1.w};
#pragma unroll
        for (int j = 0; j < 8; ++j) {
            int k = kc * 32 + quad * 8 + j;
            a[kc][j] = (short)f2bf(fmaxf(vals[j] * scs[k] + shs[k], 0.f));
        }
    }
    v4f accv[4];
#pragma unroll
    for (int nt = 0; nt < 4; ++nt) {
        float bb = b2[nt * 16 + m16];
        v4f acc = {bb, bb, bb, bb};
        acc = __builtin_amdgcn_mfma_f32_16x16x32_bf16(a[0], bw[nt][0], acc, 0, 0, 0);
        acc = __builtin_amdgcn_mfma_f32_16x16x32_bf16(a[1], bw[nt][1], acc, 0, 0, 0);
        accv[nt] = acc;
    }
    int gid_prev = -1;
    float psum[4] = {0.f, 0.f, 0.f, 0.f};
#pragma unroll
    for (int reg = 0; reg < 4; ++reg) {
        int gid = batch[row0 + quad * 4 + reg];
        if (gid != gid_prev) {
            if (gid_prev >= 0)
#pragma unroll
                for (int nt = 0; nt < 4; ++nt)
                    atomicAdd(&out[(size_t)gid_prev * F + nt * 16 + m16], psum[nt]);
            gid_prev = gid;
            psum[0] = psum[1] = psum[2] = psum[3] = 0.f;
        }
#pragma unroll
        for (int nt = 0; nt < 4; ++nt) psum[nt] += accv[nt][reg];
    }
    if (gid_prev >= 0)
#pragma unroll
        for (int nt = 0; nt < 4; ++nt)
            atomicAdd(&out[(size_t)gid_prev * F + nt * 16 + m16], psum[nt]);
}

// ---- launcher -----------------------------------------------------------

extern "C" void kernel_launch(void* const* d_in, const int* in_sizes, int n_in,
                              void* d_out, int out_size, void* d_ws, size_t ws_size,
                              hipStream_t stream) {
    const float* x      = (const float*)d_in[0];
    const int*   ei     = (const int*)d_in[1];
    const int*   batch  = (const int*)d_in[2];
    const float* convW1 = (const float*)d_in[3];
    const float* convb1 = (const float*)d_in[4];
    const float* convg  = (const float*)d_in[5];
    const float* convbt = (const float*)d_in[6];
    const float* convW2 = (const float*)d_in[7];
    const float* convb2 = (const float*)d_in[8];
    const float* mlpW1  = (const float*)d_in[9];
    const float* mlpb1  = (const float*)d_in[10];
    const float* mlpg   = (const float*)d_in[11];
    const float* mlpbt  = (const float*)d_in[12];
    const float* mlpW2  = (const float*)d_in[13];
    const float* mlpb2  = (const float*)d_in[14];

    const int N = in_sizes[0] / F;             // 50000
    const int E = in_sizes[1] / 2;             // 800000
    const int L = in_sizes[3] / (F * F);       // 5

    const int* src = ei;
    const int* dst = ei + E;

    char* w = (char*)d_ws;
    size_t off = 0;
    auto alloc = [&](size_t bytes) {
        void* p = w + off;
        off = (off + bytes + 255) & ~(size_t)255;
        return p;
    };
    u16*   x16     = (u16*)alloc((size_t)(N + 1) * F * 2);   // +1: zero pad row
    u16*   hA16    = (u16*)alloc((size_t)(N + 1) * F * 2);
    u16*   hB16    = (u16*)alloc((size_t)(N + 1) * F * 2);
    u16*   Ytmp16  = (u16*)alloc((size_t)N * F * 2);
    float* Yf      = (float*)alloc((size_t)N * F * 4);
    int*   deg     = (int*)alloc((size_t)N * 4);
    int*   offs    = (int*)alloc((size_t)(N + 1) * 4);
    int*   cursor  = (int*)alloc((size_t)N * 4);
    int*   csr_src = (int*)alloc((size_t)E * 4);
    int*   part    = (int*)alloc((size_t)SCAN_B * 4);
    float* stats   = (float*)alloc((size_t)(L + 1) * 128 * 4);
    u16*   Wt      = (u16*)alloc((size_t)L * F * F * 2);     // pre-transposed W1s

    hipMemsetAsync(deg, 0, (size_t)N * 4, stream);
    hipMemsetAsync(stats, 0, (size_t)(L + 1) * 128 * 4, stream);
    hipMemsetAsync(d_out, 0, (size_t)out_size * 4, stream);

    const int edgeBlocks = (E + TPB - 1) / TPB;

    k_hist<<<edgeBlocks, TPB, 0, stream>>>(dst, deg, E);
    k_scan_part<<<SCAN_B, TPB, 0, stream>>>(deg, part, N);
    k_scan_apply<<<SCAN_B, TPB, 0, stream>>>(deg, part, offs, cursor, N);
    k_fill<<<edgeBlocks, TPB, 0, stream>>>(src, dst, cursor, csr_src, E);
    k_wprep<<<L, TPB, 0, stream>>>(convW1, Wt);

    const int blocksA = (N + 4 * NPW - 1) / (4 * NPW);   // 1563 (32 nodes/block)
    const int blocksB = (N + 63) / 64;                   // MFMA tiles

    k_prep<<<blocksB, TPB, 0, stream>>>(x, x16, mlpW1, mlpb1, Yf, hA16, hB16, N);

    const u16* h_cur = x16;
    for (int l = 0; l < L; ++l) {
        u16* h_next = (l & 1) ? hB16 : hA16;
        k_gather_gemm<<<blocksA, TPB, 0, stream>>>(h_cur, offs, csr_src,
                                                   Wt + (size_t)l * F * F, convb1 + l * F,
                                                   Ytmp16, stats + l * 128, N);
        k_layerB<<<blocksB, TPB, 0, stream>>>(Ytmp16, stats + l * 128,
                                              convg + l * F, convbt + l * F,
                                              convW2 + l * F * F, convb2 + l * F,
                                              mlpW1 + (l + 1) * F * F,
                                              h_next, Yf, stats + L * 128,
                                              N, l == L - 1);
        h_cur = h_next;
    }

    k_final<<<blocksB, TPB, 0, stream>>>(Yf, stats + L * 128, mlpg, mlpbt,
                                         mlpW2, mlpb2, batch, (float*)d_out, N);
}